// Round 7
// baseline (499.444 us; speedup 1.0000x reference)
//
#include <hip/hip_runtime.h>
#include <hip/hip_bf16.h>
#include <math.h>

// ---------------------------------------------------------------------------
// NGLU: B=512 parcels x P=200 poi nodes. N=102400, E=1638400, HID=256.
// Round 6: algebraic cuts.
//  - Layer 1 reassociated: (Adj@Xn)@W1 instead of Adj@(Xn@W1): agg K-input
//    width 64 (4.3 GF instead of 17.2), no transposed-Y round trip.
//  - pp eliminated: el = PN@(Wpp@u)+bpp.u ; p2i = qPN@(Wpp@Wgin)/3 + bias.
//  - Layer 2 unchanged (transform->Yt->agg256).
// ---------------------------------------------------------------------------

#define N_NODES 102400
#define B_PAR   512
#define P_NODES 200
#define E_EDGES 1638400
#define HIDF    256

typedef __attribute__((ext_vector_type(8))) short bf16x8;
typedef __attribute__((ext_vector_type(4))) float f32x4;

__device__ __forceinline__ unsigned short f2bf(float x) {
    unsigned u = __builtin_bit_cast(unsigned, x);
    u += 0x7fffu + ((u >> 16) & 1u);               // RNE (finite data only)
    return (unsigned short)(u >> 16);
}
__device__ __forceinline__ float bf2f(unsigned short h) {
    return __builtin_bit_cast(float, (unsigned)h << 16);
}
// LDS tile [rows][64 k] bf16 = 128B/row; 16B-chunk XOR swizzle.
__device__ __forceinline__ int lds_off(int row, int kbyte) {
    return row * 128 + ((((kbyte >> 4) ^ (row & 7)) << 4) | (kbyte & 15));
}
template<bool BF16SRC>
__device__ __forceinline__ bf16x8 load_row8(const void* p, size_t elemoff) {
    if constexpr (BF16SRC) {
        return *(const bf16x8*)((const unsigned short*)p + elemoff);
    } else {
        const float* ap = (const float*)p + elemoff;
        float4 lo = *(const float4*)ap;
        float4 hi = *(const float4*)(ap + 4);
        union { bf16x8 v; unsigned short u[8]; } pk;
        pk.u[0] = f2bf(lo.x); pk.u[1] = f2bf(lo.y);
        pk.u[2] = f2bf(lo.z); pk.u[3] = f2bf(lo.w);
        pk.u[4] = f2bf(hi.x); pk.u[5] = f2bf(hi.y);
        pk.u[6] = f2bf(hi.z); pk.u[7] = f2bf(hi.w);
        return pk.v;
    }
}
__device__ __forceinline__ bf16x8 u8x8_to_bf16(uint2 w) {
    union { bf16x8 v; unsigned short u[8]; } r;
#pragma unroll
    for (int b = 0; b < 4; ++b) {
        r.u[b]     = (unsigned short)(__builtin_bit_cast(unsigned,
                        (float)((w.x >> (8 * b)) & 255u)) >> 16);   // exact: ints<256
        r.u[4 + b] = (unsigned short)(__builtin_bit_cast(unsigned,
                        (float)((w.y >> (8 * b)) & 255u)) >> 16);
    }
    return r.v;
}

// --------------------- 256x256-tile 8-wave MFMA GEMM ------------------------
// D[M,Nc] = A[M,K] @ B[Nc,K]^T  (row-major [m][k] / [n][k] operands)
// OMODE: 0=f32 [M][Nc], 1=bf16 [M][Nc], 2=bf16 parcel-transposed
//        (row=f, col=g -> Yt[g/200][f][g%200] of [512][256][256]).
// SCMODE: 0 none, 1 scale[row], 2 scale[col].
template<bool ABF16, bool BBF16, int OMODE, int SCMODE, bool BIASF, bool RELUF>
__global__ __launch_bounds__(512, 2) void mm256_k(
    const void* __restrict__ Ain, const void* __restrict__ Bin,
    void* __restrict__ Cout, int M, int Nc, int K,
    const float* __restrict__ scale, const float* __restrict__ bias)
{
    __shared__ bf16x8 smem_v[4096];                 // 64 KiB
    unsigned char* Asm = (unsigned char*)smem_v;
    unsigned char* Bsm = Asm + 32768;

    const int tid  = threadIdx.x;
    const int m0   = blockIdx.y * 256;
    const int n0   = blockIdx.x * 256;
    const int sr   = tid >> 3, sc = tid & 7;
    const int lane = tid & 63;
    const int wave = tid >> 6;
    const int wm   = wave >> 2, wn = wave & 3;      // wave tile: 128m x 64n
    const int frow = lane & 15;
    const int fko  = (lane >> 4) << 4;

    f32x4 acc[8][4];
    const f32x4 fz = {0.f, 0.f, 0.f, 0.f};
#pragma unroll
    for (int i = 0; i < 8; ++i)
#pragma unroll
        for (int j = 0; j < 4; ++j) acc[i][j] = fz;

    bf16x8 areg[4], breg[4];
    auto load_tiles = [&](int k0) {
#pragma unroll
        for (int i = 0; i < 4; ++i) {
            int row = sr + 64 * i;
            areg[i] = load_row8<ABF16>(Ain, (size_t)(m0 + row) * K + k0 + sc * 8);
            breg[i] = load_row8<BBF16>(Bin, (size_t)(n0 + row) * K + k0 + sc * 8);
        }
    };

    load_tiles(0);
    for (int k0 = 0; k0 < K; k0 += 64) {
        __syncthreads();
#pragma unroll
        for (int i = 0; i < 4; ++i) {
            *(bf16x8*)(Asm + lds_off(sr + 64 * i, sc * 16)) = areg[i];
            *(bf16x8*)(Bsm + lds_off(sr + 64 * i, sc * 16)) = breg[i];
        }
        __syncthreads();
        if (k0 + 64 < K) load_tiles(k0 + 64);
#pragma unroll
        for (int ks = 0; ks < 2; ++ks) {
            const int kb = ks * 64 + fko;
            bf16x8 bfr[4];
#pragma unroll
            for (int t = 0; t < 4; ++t)
                bfr[t] = *(const bf16x8*)(Bsm + lds_off(wn * 64 + t * 16 + frow, kb));
#pragma unroll
            for (int mi = 0; mi < 8; ++mi) {
                bf16x8 af = *(const bf16x8*)(Asm + lds_off(wm * 128 + mi * 16 + frow, kb));
#pragma unroll
                for (int ni = 0; ni < 4; ++ni)
                    acc[mi][ni] = __builtin_amdgcn_mfma_f32_16x16x32_bf16(
                        af, bfr[ni], acc[mi][ni], 0, 0, 0);
            }
        }
    }

    const int r4 = (lane >> 4) << 2;                // C/D: col=l&15, row=(l>>4)*4+j
#pragma unroll
    for (int mi = 0; mi < 8; ++mi) {
#pragma unroll
        for (int ni = 0; ni < 4; ++ni) {
            int col = n0 + wn * 64 + ni * 16 + frow;
#pragma unroll
            for (int j = 0; j < 4; ++j) {
                int row = m0 + wm * 128 + mi * 16 + r4 + j;
                float v = acc[mi][ni][j];
                if (SCMODE == 1) v *= scale[row];
                if (SCMODE == 2) v *= scale[col];
                if (BIASF)       v += bias[col];
                if (RELUF)       v = fmaxf(v, 0.f);
                if (OMODE == 0) {
                    ((float*)Cout)[(size_t)row * Nc + col] = v;
                } else if (OMODE == 1) {
                    ((unsigned short*)Cout)[(size_t)row * Nc + col] = f2bf(v);
                } else {
                    int p = col / 200, r = col - p * 200;
                    ((unsigned short*)Cout)[((size_t)p * 256 + row) * 256 + r] = f2bf(v);
                }
            }
        }
    }
}

// ------------- GCN aggregation L2: one block per parcel, 256x256 ------------
// Out[p*200+d][f] = (sum_s Adj[p][d][s] * Yt[p][f][s]) * nrm[g] + bias[f]
__global__ __launch_bounds__(512, 2) void agg256_k(
    const unsigned char* __restrict__ Adj, const unsigned short* __restrict__ Yt,
    unsigned short* __restrict__ Outb, const float* __restrict__ nrm,
    const float* __restrict__ bias, int relu)
{
    __shared__ bf16x8 smem_v[4096];
    unsigned char* Asm = (unsigned char*)smem_v;
    unsigned char* Bsm = Asm + 32768;

    const int tid  = threadIdx.x;
    const int p    = blockIdx.x;
    const int sr   = tid >> 3, sc = tid & 7;
    const int lane = tid & 63;
    const int wave = tid >> 6;
    const int wm   = wave >> 2, wn = wave & 3;
    const int frow = lane & 15;
    const int fko  = (lane >> 4) << 4;
    const size_t abase = (size_t)p * 65536;
    const size_t ybase = (size_t)p * 65536;

    f32x4 acc[8][4];
    const f32x4 fz = {0.f, 0.f, 0.f, 0.f};
#pragma unroll
    for (int i = 0; i < 8; ++i)
#pragma unroll
        for (int j = 0; j < 4; ++j) acc[i][j] = fz;

    uint2  awreg[4];
    bf16x8 breg[4];
    auto load_tiles = [&](int k0) {
#pragma unroll
        for (int i = 0; i < 4; ++i) {
            int row = sr + 64 * i;
            awreg[i] = *(const uint2*)(Adj + abase + (size_t)row * 256 + k0 + sc * 8);
            breg[i]  = *(const bf16x8*)(Yt + ybase + (size_t)row * 256 + k0 + sc * 8);
        }
    };

    load_tiles(0);
#pragma unroll
    for (int t4 = 0; t4 < 4; ++t4) {
        __syncthreads();
#pragma unroll
        for (int i = 0; i < 4; ++i) {
            *(bf16x8*)(Asm + lds_off(sr + 64 * i, sc * 16)) = u8x8_to_bf16(awreg[i]);
            *(bf16x8*)(Bsm + lds_off(sr + 64 * i, sc * 16)) = breg[i];
        }
        __syncthreads();
        if (t4 < 3) load_tiles((t4 + 1) * 64);
#pragma unroll
        for (int ks = 0; ks < 2; ++ks) {
            const int kb = ks * 64 + fko;
            bf16x8 bfr[4];
#pragma unroll
            for (int t = 0; t < 4; ++t)
                bfr[t] = *(const bf16x8*)(Bsm + lds_off(wn * 64 + t * 16 + frow, kb));
#pragma unroll
            for (int mi = 0; mi < 8; ++mi) {
                bf16x8 af = *(const bf16x8*)(Asm + lds_off(wm * 128 + mi * 16 + frow, kb));
#pragma unroll
                for (int ni = 0; ni < 4; ++ni)
                    acc[mi][ni] = __builtin_amdgcn_mfma_f32_16x16x32_bf16(
                        af, bfr[ni], acc[mi][ni], 0, 0, 0);
            }
        }
    }

    const int r4 = (lane >> 4) << 2;
#pragma unroll
    for (int mi = 0; mi < 8; ++mi) {
#pragma unroll
        for (int ni = 0; ni < 4; ++ni) {
            int col = wn * 64 + ni * 16 + frow;
#pragma unroll
            for (int j = 0; j < 4; ++j) {
                int d = wm * 128 + mi * 16 + r4 + j;
                if (d < 200) {
                    int g = p * 200 + d;
                    float v = acc[mi][ni][j] * nrm[g] + bias[col];
                    if (relu) v = fmaxf(v, 0.f);
                    Outb[(size_t)g * 256 + col] = f2bf(v);
                }
            }
        }
    }
}

// --------- GCN aggregation L1 (reassociated): AX = Adj @ Xnt^T --------------
// AX[p*200+d][k] = sum_s Adj[p][d][s] * Xnt[p][k][s]   (k in [0,64))
__global__ __launch_bounds__(512) void agg1_k(
    const unsigned char* __restrict__ Adj, const unsigned short* __restrict__ Xnt,
    unsigned short* __restrict__ AX)
{
    __shared__ bf16x8 smem_v[2560];                 // 40 KiB: A 32K + B 8K
    unsigned char* Asm = (unsigned char*)smem_v;
    unsigned char* Bsm = Asm + 32768;

    const int tid  = threadIdx.x;
    const int p    = blockIdx.x;
    const int arow = tid >> 1, ah = tid & 1;        // A: 256 rows x 32B halves
    const int brow = tid >> 3, sc = tid & 7;        // B: 64 rows x 8 chunks
    const int lane = tid & 63;
    const int wave = tid >> 6;                      // 8 waves: rows wave*32
    const int frow = lane & 15;
    const int fko  = (lane >> 4) << 4;
    const size_t abase = (size_t)p * 65536;
    const size_t xbase = (size_t)p * 16384;

    f32x4 acc[2][4];
    const f32x4 fz = {0.f, 0.f, 0.f, 0.f};
#pragma unroll
    for (int i = 0; i < 2; ++i)
#pragma unroll
        for (int j = 0; j < 4; ++j) acc[i][j] = fz;

    uint4  aw[2];
    bf16x8 bg;
    auto load_tiles = [&](int k0) {
        const uint4* ap = (const uint4*)(Adj + abase + (size_t)arow * 256 + k0 + ah * 32);
        aw[0] = ap[0];
        aw[1] = ap[1];
        bg = *(const bf16x8*)(Xnt + xbase + (size_t)brow * 256 + k0 + sc * 8);
    };

    load_tiles(0);
#pragma unroll
    for (int t4 = 0; t4 < 4; ++t4) {
        __syncthreads();
        {
            uint2 l0 = {aw[0].x, aw[0].y}, h0 = {aw[0].z, aw[0].w};
            uint2 l1 = {aw[1].x, aw[1].y}, h1 = {aw[1].z, aw[1].w};
            int base = ah * 64;
            *(bf16x8*)(Asm + lds_off(arow, base +  0)) = u8x8_to_bf16(l0);
            *(bf16x8*)(Asm + lds_off(arow, base + 16)) = u8x8_to_bf16(h0);
            *(bf16x8*)(Asm + lds_off(arow, base + 32)) = u8x8_to_bf16(l1);
            *(bf16x8*)(Asm + lds_off(arow, base + 48)) = u8x8_to_bf16(h1);
            *(bf16x8*)(Bsm + lds_off(brow, sc * 16)) = bg;
        }
        __syncthreads();
        if (t4 < 3) load_tiles((t4 + 1) * 64);
#pragma unroll
        for (int ks = 0; ks < 2; ++ks) {
            const int kb = ks * 64 + fko;
            bf16x8 bfr[4];
#pragma unroll
            for (int t = 0; t < 4; ++t)
                bfr[t] = *(const bf16x8*)(Bsm + lds_off(t * 16 + frow, kb));
#pragma unroll
            for (int mi = 0; mi < 2; ++mi) {
                bf16x8 af = *(const bf16x8*)(Asm + lds_off(wave * 32 + mi * 16 + frow, kb));
#pragma unroll
                for (int ni = 0; ni < 4; ++ni)
                    acc[mi][ni] = __builtin_amdgcn_mfma_f32_16x16x32_bf16(
                        af, bfr[ni], acc[mi][ni], 0, 0, 0);
            }
        }
    }

    const int r4 = (lane >> 4) << 2;
#pragma unroll
    for (int mi = 0; mi < 2; ++mi) {
#pragma unroll
        for (int ni = 0; ni < 4; ++ni) {
            int col = ni * 16 + frow;
#pragma unroll
            for (int j = 0; j < 4; ++j) {
                int d = wave * 32 + mi * 16 + r4 + j;
                if (d < 200)
                    AX[((size_t)(p * 200 + d)) * 64 + col] = f2bf(acc[mi][ni][j]);
            }
        }
    }
}

// -------- Xnt[p][k][s] = g_poi[p*200+s][k] * nrm[p*200+s] (pad s>=200) -------
__global__ __launch_bounds__(256) void xt_k(const float* __restrict__ gp,
                                            const float* __restrict__ nrm,
                                            unsigned short* __restrict__ Xnt)
{
    __shared__ unsigned short lsh[64][264];
    const int p = blockIdx.x, tid = threadIdx.x;
    for (int idx = tid; idx < 256 * 16; idx += 256) {
        int s = idx >> 4, kc = idx & 15;
        float4 v = {0.f, 0.f, 0.f, 0.f};
        float nr = 0.f;
        if (s < 200) {
            v = *(const float4*)(gp + ((size_t)(p * 200 + s)) * 64 + kc * 4);
            nr = nrm[p * 200 + s];
        }
        lsh[kc * 4 + 0][s] = f2bf(v.x * nr);
        lsh[kc * 4 + 1][s] = f2bf(v.y * nr);
        lsh[kc * 4 + 2][s] = f2bf(v.z * nr);
        lsh[kc * 4 + 3][s] = f2bf(v.w * nr);
    }
    __syncthreads();
    for (int idx = tid; idx < 64 * 32; idx += 256) {
        int k = idx >> 5, ch = idx & 31;
        uint4 o = *(const uint4*)(&lsh[k][ch * 8]);
        *(uint4*)(Xnt + (size_t)p * 16384 + k * 256 + ch * 8) = o;
    }
}

// ----------------------- 64x64 MFMA GEMM (small shapes) ---------------------
template<bool ABF16, bool BBF16, int OMODE, bool BIASF, bool RELUF,
         bool MEDOUT, int KCHUNK>
__global__ __launch_bounds__(256) void mm64_k(
    const void* __restrict__ Ain, const void* __restrict__ Bin,
    void* __restrict__ Cout, int M, int Nc, int K,
    const float* __restrict__ bias, float alpha)
{
    __shared__ bf16x8 smem_v[1024];                 // 16 KiB
    unsigned char* Asm = (unsigned char*)smem_v;
    unsigned char* Bsm = Asm + 8192;

    const int tid  = threadIdx.x;
    const int m0   = blockIdx.y * 64;
    const int n0   = blockIdx.x * 64;
    const int sr   = tid >> 3, sc = tid & 7;
    const int lane = tid & 63;
    const int wm   = (tid >> 7) & 1, wn = (tid >> 6) & 1;
    const int frow = lane & 15;
    const int fko  = (lane >> 4) << 4;

    int kbeg = 0, kend = K;
    float* Cf = (float*)Cout;
    if (KCHUNK > 0) {
        kbeg = blockIdx.z * KCHUNK; kend = kbeg + KCHUNK;
        Cf += (size_t)blockIdx.z * M * Nc;
    }

    f32x4 acc[2][2];
    const f32x4 fz = {0.f, 0.f, 0.f, 0.f};
#pragma unroll
    for (int i = 0; i < 2; ++i)
#pragma unroll
        for (int j = 0; j < 2; ++j) acc[i][j] = fz;

    bf16x8 areg[2], breg[2];
    auto load_tiles = [&](int k0) {
#pragma unroll
        for (int i = 0; i < 2; ++i) {
            int row = sr + 32 * i;
            areg[i] = load_row8<ABF16>(Ain, (size_t)(m0 + row) * K + k0 + sc * 8);
            breg[i] = load_row8<BBF16>(Bin, (size_t)(n0 + row) * K + k0 + sc * 8);
        }
    };

    load_tiles(kbeg);
    for (int k0 = kbeg; k0 < kend; k0 += 64) {
        __syncthreads();
#pragma unroll
        for (int i = 0; i < 2; ++i) {
            *(bf16x8*)(Asm + lds_off(sr + 32 * i, sc * 16)) = areg[i];
            *(bf16x8*)(Bsm + lds_off(sr + 32 * i, sc * 16)) = breg[i];
        }
        __syncthreads();
        if (k0 + 64 < kend) load_tiles(k0 + 64);
#pragma unroll
        for (int ks = 0; ks < 2; ++ks) {
            const int kb = ks * 64 + fko;
            bf16x8 af[2], bfr[2];
#pragma unroll
            for (int t = 0; t < 2; ++t)
                af[t] = *(const bf16x8*)(Asm + lds_off(wm * 32 + t * 16 + frow, kb));
#pragma unroll
            for (int t = 0; t < 2; ++t)
                bfr[t] = *(const bf16x8*)(Bsm + lds_off(wn * 32 + t * 16 + frow, kb));
#pragma unroll
            for (int mi = 0; mi < 2; ++mi)
#pragma unroll
                for (int ni = 0; ni < 2; ++ni)
                    acc[mi][ni] = __builtin_amdgcn_mfma_f32_16x16x32_bf16(
                        af[mi], bfr[ni], acc[mi][ni], 0, 0, 0);
        }
    }

    const int r4 = (lane >> 4) << 2;
#pragma unroll
    for (int mi = 0; mi < 2; ++mi) {
#pragma unroll
        for (int ni = 0; ni < 2; ++ni) {
            int col = n0 + wn * 32 + ni * 16 + frow;
#pragma unroll
            for (int j = 0; j < 4; ++j) {
                int row = m0 + wm * 32 + mi * 16 + r4 + j;
                float v = acc[mi][ni][j] * alpha;
                if (BIASF)  v += bias[col];
                if (RELUF)  v = fmaxf(v, 0.f);
                if (MEDOUT) v += 0.5f;
                if (OMODE == 0) {
                    Cf[(size_t)row * Nc + col] = v;
                } else {
                    ((unsigned short*)Cout)[(size_t)row * Nc + col] = f2bf(v);
                }
            }
        }
    }
}

// ------------------------- graph preprocessing -----------------------------
__global__ __launch_bounds__(256) void edge_diag_k(
    const int* __restrict__ esrc, const int* __restrict__ edst,
    unsigned char* __restrict__ A)
{
    int id = blockIdx.x * 256 + threadIdx.x;        // E + N = 1740800
    size_t bo;
    if (id < E_EDGES) {
        int s = esrc[id], d = edst[id];
        int p = d / 200;
        int dl = d - p * 200, sl = s - p * 200;
        bo = (((size_t)(p * 256 + dl)) << 8) + (unsigned)sl;
    } else {
        int i2 = id - E_EDGES;                      // < N
        int p = i2 / 200, d = i2 - p * 200;
        bo = (((size_t)(p * 256 + d)) << 8) + (unsigned)d;
    }
    atomicAdd((unsigned int*)(A + (bo & ~(size_t)3)), 1u << ((bo & 3) * 8));
}

__global__ __launch_bounds__(256) void norm2_k(const unsigned char* __restrict__ A,
                                               float* __restrict__ nrm)
{
    int g = blockIdx.x * 256 + threadIdx.x;
    int p = g / 200, d = g - p * 200;
    const uint4* row = (const uint4*)(A + (((size_t)(p * 256 + d)) << 8));
    unsigned s = 0;
#pragma unroll
    for (int i = 0; i < 16; ++i) {
        uint4 w = row[i];
        unsigned a = w.x, b = w.y, c = w.z, e = w.w;
        s += (a & 255) + ((a >> 8) & 255) + ((a >> 16) & 255) + (a >> 24);
        s += (b & 255) + ((b >> 8) & 255) + ((b >> 16) & 255) + (b >> 24);
        s += (c & 255) + ((c >> 8) & 255) + ((c >> 16) & 255) + (c >> 24);
        s += (e & 255) + ((e >> 8) & 255) + ((e >> 16) & 255) + (e >> 24);
    }
    nrm[g] = rsqrtf((float)s);                      // row-sum = in-deg + self
}

// ------------- all weight transposes/casts + img cast -----------------------
__global__ __launch_bounds__(256) void prep_k(
    const float* __restrict__ W1, const float* __restrict__ W2,
    const float* __restrict__ Whg,
    const float* __restrict__ Wpg, const float* __restrict__ Whrs,
    const float* __restrict__ Wgin, const float* __restrict__ Wgw,
    const float* __restrict__ Wph, const float* __restrict__ img,
    unsigned short* __restrict__ W1t, unsigned short* __restrict__ W2t,
    unsigned short* __restrict__ Whgt,
    unsigned short* __restrict__ Wpgt, unsigned short* __restrict__ Whrst,
    unsigned short* __restrict__ Wgint, unsigned short* __restrict__ Wmt,
    unsigned short* __restrict__ Wphb, unsigned short* __restrict__ imgb)
{
    int b = blockIdx.x, tid = threadIdx.x;
    if (b < 64) {                 // W1t [256][64]
        int id = b * 256 + tid; int n = id >> 6, k = id & 63;
        W1t[id] = f2bf(W1[(size_t)k * 256 + n]);
    } else if (b < 320) {         // W2t [256][256]
        int id = (b - 64) * 256 + tid; int n = id >> 8, k = id & 255;
        W2t[id] = f2bf(W2[(size_t)k * 256 + n]);
    } else if (b < 576) {         // Whgt
        int id = (b - 320) * 256 + tid; int n = id >> 8, k = id & 255;
        Whgt[id] = f2bf(Whg[(size_t)k * 256 + n]);
    } else if (b < 832) {         // Wpgt
        int id = (b - 576) * 256 + tid; int n = id >> 8, k = id & 255;
        Wpgt[id] = f2bf(Wpg[(size_t)k * 256 + n]);
    } else if (b < 2880) {        // Whrst [256][2048]
        int id = (b - 832) * 256 + tid; int n = id >> 11, k = id & 2047;
        Whrst[id] = f2bf(Whrs[(size_t)k * 256 + n]);
    } else if (b < 3648) {        // Wgint [256][768], k-order = h*256+t
        int id = (b - 2880) * 256 + tid; int j = id / 768, k2 = id - j * 768;
        int t = k2 & 255, h = k2 >> 8;
        Wgint[id] = f2bf(Wgin[(size_t)t * 768 + h * 256 + j]);
    } else if (b < 3904) {        // Wmt [256 j][256 t] = mean_h Wgw / (1+1e-9)
        int id = (b - 3648) * 256 + tid; int j = id >> 8, t = id & 255;
        const float c3 = (1.f / 3.f) * (1.f / (1.f + 1e-9f));
        float s = Wgw[(size_t)t * 768 + j] + Wgw[(size_t)t * 768 + 256 + j] +
                  Wgw[(size_t)t * 768 + 512 + j];
        Wmt[id] = f2bf(s * c3);
    } else if (b < 4160) {        // Wphb cast
        int id = (b - 3904) * 256 + tid;
        Wphb[id] = f2bf(Wph[id]);
    } else {                      // imgb cast [512][2048]
        int id = (b - 4160) * 256 + tid;
        imgb[id] = f2bf(img[id]);
    }
}

// --- WpG[j][(h,c)] = sum_t Wpp[c][t]*Wgin[t][h*256+j]; bgg[j] (bias fold) ----
__global__ __launch_bounds__(256) void wpg_k(
    const float* __restrict__ Wpp, const float* __restrict__ Wgin,
    const float* __restrict__ bpp,
    unsigned short* __restrict__ WpG, float* __restrict__ bgg)
{
    __shared__ float wsh[256];
    const int b = blockIdx.x, j = threadIdx.x;
    if (b < 768) {
        int h = b >> 8, c = b & 255;
        wsh[j] = Wpp[(size_t)c * 256 + j];
        __syncthreads();
        float acc = 0.f;
        for (int t = 0; t < 256; ++t)
            acc += wsh[t] * Wgin[(size_t)t * 768 + h * 256 + j];
        WpG[(size_t)j * 768 + h * 256 + c] = f2bf(acc);
    } else {
        float s = 0.f;
        for (int h = 0; h < 3; ++h)
            for (int t = 0; t < 256; ++t)
                s += bpp[t] * Wgin[(size_t)t * 768 + h * 256 + j];
        bgg[j] = s * (1.f / 3.f);
    }
}

// --------------------------- hrs split-K reduce -----------------------------
__global__ __launch_bounds__(256) void hrs_reduce_k(
    const float* __restrict__ part, const float* __restrict__ bhrs,
    float* __restrict__ hrs, unsigned short* __restrict__ hrsb)
{
    int id = blockIdx.x * 256 + threadIdx.x;        // 131072
    float s = bhrs[id & 255];
#pragma unroll
    for (int z = 0; z < 8; ++z) s += part[(size_t)z * 131072 + id];
    hrs[id] = s;
    hrsb[id] = f2bf(s);
}

// ------------------------------ pooling (vectorized) ------------------------
__global__ __launch_bounds__(256) void pool_k(const unsigned short* __restrict__ X,
                                              float* __restrict__ Pl,
                                              unsigned short* __restrict__ Plb)
{
    __shared__ float sh[2048];
    const int b = blockIdx.x, tid = threadIdx.x;
    const int cg = tid & 31, rg = tid >> 5;
    const size_t base = (size_t)b * P_NODES * HIDF + cg * 8;
    float acc[8] = {};
    for (int n = rg; n < P_NODES; n += 8) {
        union { uint4 q; unsigned short u[8]; } v;
        v.q = *(const uint4*)(X + base + (size_t)n * HIDF);
#pragma unroll
        for (int j = 0; j < 8; ++j) acc[j] += bf2f(v.u[j]);
    }
#pragma unroll
    for (int j = 0; j < 8; ++j) sh[rg * 256 + cg * 8 + j] = acc[j];
    __syncthreads();
    float s = 0.f;
#pragma unroll
    for (int r = 0; r < 8; ++r) s += sh[r * 256 + tid];
    s *= (1.f / 200.f);
    Pl[(size_t)b * 256 + tid] = s;
    Plb[(size_t)b * 256 + tid] = f2bf(s);
}

// ------------------- med = rownorm(concat(hrs, pool)) -----------------------
__global__ __launch_bounds__(256) void med_build_k(
    const float* __restrict__ hrs, const float* __restrict__ pool,
    unsigned short* __restrict__ medb)
{
    __shared__ float red[256];
    int b = blockIdx.x, f = threadIdx.x;
    float v0 = hrs[(size_t)b * 256 + f];
    float v1 = pool[(size_t)b * 256 + f];
    red[f] = v0 * v0 + v1 * v1;
    __syncthreads();
    for (int s = 128; s > 0; s >>= 1) {
        if (f < s) red[f] += red[f + s];
        __syncthreads();
    }
    float inv = rsqrtf(red[0]);
    medb[(size_t)b * 512 + f]       = f2bf(v0 * inv);
    medb[(size_t)b * 512 + 256 + f] = f2bf(v1 * inv);
}

// ---------------------- thresholded-similarity GCN --------------------------
__global__ __launch_bounds__(256) void dinv_k(const float* __restrict__ mo,
                                              float* __restrict__ dinv)
{
    __shared__ int red[256];
    int i = blockIdx.x, t = threadIdx.x;
    int c = 0;
    for (int j = t; j < 512; j += 256) c += (mo[(size_t)i * 512 + j] >= 0.9f) ? 1 : 0;
    red[t] = c; __syncthreads();
    for (int s = 128; s > 0; s >>= 1) {
        if (t < s) red[t] += red[t + s];
        __syncthreads();
    }
    if (t == 0) dinv[i] = rsqrtf((float)red[0]);
}

__global__ __launch_bounds__(256) void nadj_k(const float* __restrict__ mo,
                                              const float* __restrict__ dinv,
                                              unsigned short* __restrict__ nadjb)
{
    int i = blockIdx.x, t = threadIdx.x;
    float di = dinv[i];
    for (int j = t; j < 512; j += 256) {
        float a = (mo[(size_t)i * 512 + j] >= 0.9f || j == i) ? 1.f : 0.f;
        nadjb[(size_t)i * 512 + j] = f2bf(a * di * dinv[j]);
    }
}

// ------------------------------ GAT pieces ----------------------------------
// u2[t,h] from (Wgin,al); v2[t,h] from (Wgin,ar);
// wu[c,h] = Wpp^T-fold of u2; vv2[c,h] = Wph-fold of v2;
// erb[h] = bph.v2 ; eb0[h] = bpp.u2 ; bc[k] = bph @ Wm[:,k]
__global__ __launch_bounds__(256) void uv_k(
    const float* __restrict__ Wgin, const float* __restrict__ al,
    const float* __restrict__ ar, const float* __restrict__ Wph,
    const float* __restrict__ bph, const unsigned short* __restrict__ Wmt,
    const float* __restrict__ Wpp, const float* __restrict__ bpp,
    float* __restrict__ wu, float* __restrict__ vv2,
    float* __restrict__ erb, float* __restrict__ eb0, float* __restrict__ bc)
{
    __shared__ float ush[768];
    __shared__ float vsh[768];
    int k = threadIdx.x;
#pragma unroll
    for (int h = 0; h < 3; ++h) {
        float su = 0.f, sv = 0.f;
        for (int t = 0; t < 256; ++t) {
            float w = Wgin[(size_t)k * 768 + h * 256 + t];
            su += w * al[h * 256 + t];
            sv += w * ar[h * 256 + t];
        }
        ush[k * 3 + h] = su;
        vsh[k * 3 + h] = sv;
    }
    __syncthreads();
    float a0 = 0.f, a1 = 0.f, a2 = 0.f;
    float w0 = 0.f, w1 = 0.f, w2 = 0.f, s = 0.f;
    for (int t = 0; t < 256; ++t) {
        float wp = Wph[(size_t)k * 256 + t];
        a0 += wp * vsh[t * 3 + 0];
        a1 += wp * vsh[t * 3 + 1];
        a2 += wp * vsh[t * 3 + 2];
        float wq = Wpp[(size_t)k * 256 + t];
        w0 += wq * ush[t * 3 + 0];
        w1 += wq * ush[t * 3 + 1];
        w2 += wq * ush[t * 3 + 2];
        s  += bph[t] * bf2f(Wmt[(size_t)k * 256 + t]);
    }
    vv2[k * 3 + 0] = a0; vv2[k * 3 + 1] = a1; vv2[k * 3 + 2] = a2;
    wu[k * 3 + 0]  = w0; wu[k * 3 + 1]  = w1; wu[k * 3 + 2]  = w2;
    bc[k] = s;
    if (k < 3) {
        float e = 0.f, e0 = 0.f;
        for (int t = 0; t < 256; ++t) {
            e  += bph[t] * vsh[t * 3 + k];
            e0 += bpp[t] * ush[t * 3 + k];
        }
        erb[k] = e;
        eb0[k] = e0;
    }
}

__global__ __launch_bounds__(256) void er_k(const float* __restrict__ hrs,
                                            const float* __restrict__ vv2,
                                            const float* __restrict__ erb,
                                            const float* __restrict__ eb0,
                                            float* __restrict__ er)
{
    int id = blockIdx.x * 256 + threadIdx.x;
    if (id >= B_PAR * 3) return;
    int b = id / 3, h = id % 3;
    float s = erb[h] + eb0[h];
    for (int k = 0; k < 256; ++k) s += hrs[(size_t)b * 256 + k] * vv2[k * 3 + h];
    er[id] = s;
}

// Per-parcel: el = PN@wu, e = leaky(el+er), softmax over 200 nodes/head,
// qPN[b,h,:] = sum_n alpha[n,h] * PN[n,:]
__global__ __launch_bounds__(256) void gat_poi2img_k(
    const unsigned short* __restrict__ PN, const float* __restrict__ wu,
    const float* __restrict__ er, float* __restrict__ q)
{
    __shared__ float esh[600];
    __shared__ float ash[600];
    __shared__ float ush[768];
    __shared__ float mz[8];
    const int p = blockIdx.x, tid = threadIdx.x;
    const size_t base = (size_t)p * P_NODES;

    for (int i = tid; i < 768; i += 256) ush[i] = wu[i];
    __syncthreads();

    for (int it = tid; it < 600; it += 256) {
        int n = it / 3, h = it % 3;
        const unsigned short* row = PN + (base + n) * HIDF;
        float s = 0.f;
        for (int k = 0; k < 256; k += 8) {
            union { uint4 qv; unsigned short us[8]; } w;
            w.qv = *(const uint4*)(row + k);
#pragma unroll
            for (int j = 0; j < 8; ++j) s += bf2f(w.us[j]) * ush[(k + j) * 3 + h];
        }
        s += er[p * 3 + h];
        esh[it] = s > 0.f ? s : 0.2f * s;
    }
    __syncthreads();

    int wave = tid >> 6, lane = tid & 63;
    if (wave < 3) {
        float mx = -1e30f;
        for (int n = lane; n < P_NODES; n += 64) mx = fmaxf(mx, esh[n * 3 + wave]);
        for (int o = 32; o > 0; o >>= 1) mx = fmaxf(mx, __shfl_xor(mx, o));
        float sm = 0.f;
        for (int n = lane; n < P_NODES; n += 64) sm += expf(esh[n * 3 + wave] - mx);
        for (int o = 32; o > 0; o >>= 1) sm += __shfl_xor(sm, o);
        if (lane == 0) { mz[wave] = mx; mz[4 + wave] = sm; }
    }
    __syncthreads();

    for (int it = tid; it < 600; it += 256) {
        int h = it % 3;
        ash[it] = expf(esh[it] - mz[h]) / (mz[4 + h] + 1e-9f);
    }
    __syncthreads();

    float a0 = 0.f, a1 = 0.f, a2 = 0.f;
    for (int n = 0; n < P_NODES; ++n) {
        float vv = bf2f(PN[(base + n) * HIDF + tid]);
        a0 += ash[n * 3 + 0] * vv;
        a1 += ash[n * 3 + 1] * vv;
        a2 += ash[n * 3 + 2] * vv;
    }
    q[((size_t)p * 3 + 0) * 256 + tid] = a0;
    q[((size_t)p * 3 + 1) * 256 + tid] = a1;
    q[((size_t)p * 3 + 2) * 256 + tid] = a2;
}

// --------------------------- final projection -------------------------------
__global__ __launch_bounds__(256) void final_k(
    const float* __restrict__ i2p, const float* __restrict__ hpagg,
    const float* __restrict__ p2i,
    const float* __restrict__ Wfc, const float* __restrict__ bfc,
    float* __restrict__ out)
{
    int id = blockIdx.x * 256 + threadIdx.x;
    if (id >= B_PAR * 12) return;
    int b = id / 12, o = id % 12;
    float acc = bfc[o];
    const float* s0 = i2p + (size_t)b * 256;          // img2poi_pooled
    const float* s1 = hpagg + (size_t)b * 512 + 256;  // poi_agg
    const float* s2 = p2i + (size_t)b * 256;          // poi2img
    const float* s3 = hpagg + (size_t)b * 512;        // hrs_agg
    for (int k = 0; k < 256; ++k) {
        acc += s0[k] * Wfc[(size_t)(0 * 256 + k) * 12 + o];
        acc += s1[k] * Wfc[(size_t)(1 * 256 + k) * 12 + o];
        acc += s2[k] * Wfc[(size_t)(2 * 256 + k) * 12 + o];
        acc += s3[k] * Wfc[(size_t)(3 * 256 + k) * 12 + o];
    }
    out[id] = acc;
}

// ---------------------------------------------------------------------------
extern "C" void kernel_launch(void* const* d_in, const int* in_sizes, int n_in,
                              void* d_out, int out_size, void* d_ws, size_t ws_size,
                              hipStream_t stream)
{
    const float* g_poi = (const float*)d_in[0];
    const float* img   = (const float*)d_in[1];
    const int*   esrc  = (const int*)d_in[2];
    const int*   edst  = (const int*)d_in[3];
    const float* W1    = (const float*)d_in[4];
    const float* b1    = (const float*)d_in[5];
    const float* W2    = (const float*)d_in[6];
    const float* b2    = (const float*)d_in[7];
    const float* Whrs  = (const float*)d_in[8];
    const float* bhrs  = (const float*)d_in[9];
    const float* Wph   = (const float*)d_in[10];
    const float* bph   = (const float*)d_in[11];
    const float* Wpp   = (const float*)d_in[12];
    const float* bpp   = (const float*)d_in[13];
    const float* Wgin  = (const float*)d_in[14];
    const float* alin  = (const float*)d_in[15];
    const float* arin  = (const float*)d_in[16];
    const float* Wgw   = (const float*)d_in[17];
    // d_in[18]/d_in[19] (al_with/ar_with) numerically dead: each poi node has
    // exactly one incoming parcel edge -> edge-softmax weight = 1/(1+1e-9).
    const float* Whg   = (const float*)d_in[20];
    const float* Wpg   = (const float*)d_in[21];
    const float* Wfc   = (const float*)d_in[22];
    const float* bfc   = (const float*)d_in[23];

    float* out     = (float*)d_out;
    float* med_out = out + B_PAR * 12;

    char* ws = (char*)d_ws;
    size_t off = 0;
    auto take = [&](size_t bytes) { void* pv = ws + off; off += (bytes + 255) & ~(size_t)255; return pv; };

    unsigned char*  adj8 = (unsigned char*)take((size_t)B_PAR * 256 * 256);     // 33.6MB
    unsigned short* Yt   = (unsigned short*)take((size_t)B_PAR * 256 * 256 * 2);// 67.1MB
    unsigned short* Xnt  = Yt;                      // [512][64][256], dead before Yt written
    unsigned short* XPN  = (unsigned short*)take((size_t)N_NODES * 256 * 2);    // 52.4MB
    unsigned short* AX   = (unsigned short*)take((size_t)N_NODES * 64 * 2);     // 13.1MB
    float*          part = (float*)take((size_t)8 * 512 * 256 * 4);             // 4.2MB

    unsigned short* W1t   = (unsigned short*)take(256 * 64 * 2);
    unsigned short* W2t   = (unsigned short*)take(256 * 256 * 2);
    unsigned short* Whgt  = (unsigned short*)take(256 * 256 * 2);
    unsigned short* Wpgt  = (unsigned short*)take(256 * 256 * 2);
    unsigned short* Whrst = (unsigned short*)take((size_t)256 * 2048 * 2);
    unsigned short* Wgint = (unsigned short*)take((size_t)256 * 768 * 2);
    unsigned short* Wmt   = (unsigned short*)take(256 * 256 * 2);
    unsigned short* Wphb  = (unsigned short*)take(256 * 256 * 2);
    unsigned short* WcT   = (unsigned short*)take(256 * 256 * 2);
    unsigned short* WpG   = (unsigned short*)take((size_t)256 * 768 * 2);
    unsigned short* imgb  = (unsigned short*)take((size_t)512 * 2048 * 2);
    unsigned short* hrsb  = (unsigned short*)take((size_t)B_PAR * 256 * 2);
    unsigned short* poolb = (unsigned short*)take((size_t)B_PAR * 256 * 2);
    unsigned short* medb  = (unsigned short*)take((size_t)B_PAR * 512 * 2);
    unsigned short* nadjb = (unsigned short*)take((size_t)B_PAR * 512 * 2);
    unsigned short* Tcatt = (unsigned short*)take((size_t)512 * 512 * 2);
    float* nrm   = (float*)take((size_t)N_NODES * 4);
    float* hrs   = (float*)take((size_t)B_PAR * 256 * 4);
    float* pool  = (float*)take((size_t)B_PAR * 256 * 4);
    float* dinv  = (float*)take((size_t)B_PAR * 4);
    float* hpagg = (float*)take((size_t)B_PAR * 512 * 4);
    float* wu    = (float*)take(768 * 4);
    float* vv2   = (float*)take(768 * 4);
    float* erb   = (float*)take(16);
    float* eb0   = (float*)take(16);
    float* bc    = (float*)take(256 * 4);
    float* bgg   = (float*)take(256 * 4);
    float* er    = (float*)take((size_t)B_PAR * 3 * 4);
    float* q     = (float*)take((size_t)B_PAR * 768 * 4);
    float* p2i   = (float*)take((size_t)B_PAR * 256 * 4);
    float* i2p   = (float*)take((size_t)B_PAR * 256 * 4);
    (void)ws_size; (void)in_sizes; (void)n_in; (void)out_size;

    // ---- preprocessing ----
    hipMemsetAsync(adj8, 0, (size_t)B_PAR * 256 * 256, stream);
    prep_k<<<8256, 256, 0, stream>>>(W1, W2, Whg, Wpg, Whrs, Wgin, Wgw,
        Wph, img, W1t, W2t, Whgt, Wpgt, Whrst, Wgint, Wmt, Wphb, imgb);
    edge_diag_k<<<(E_EDGES + N_NODES) / 256, 256, 0, stream>>>(esrc, edst, adj8);
    norm2_k<<<N_NODES / 256, 256, 0, stream>>>(adj8, nrm);
    wpg_k<<<769, 256, 0, stream>>>(Wpp, Wgin, bpp, WpG, bgg);

    // ---- hrs encoder: split-K (8x256) 64-tile MFMA + reduce ----
    mm64_k<true, true, 0, false, false, false, 256>
        <<<dim3(4, 8, 8), 256, 0, stream>>>(imgb, Whrst, part, 512, 256, 2048,
            nullptr, 1.f);
    hrs_reduce_k<<<512, 256, 0, stream>>>(part, bhrs, hrs, hrsb);

    // ---- GAT precomputes ----
    uv_k<<<1, 256, 0, stream>>>(Wgin, alin, arin, Wph, bph, Wmt, Wpp, bpp,
                                wu, vv2, erb, eb0, bc);
    er_k<<<6, 256, 0, stream>>>(hrs, vv2, erb, eb0, er);
    // WcT[j][c] = (Wph @ Wm)[c][j]
    mm64_k<true, true, 1, false, false, false, 0>
        <<<dim3(4, 4), 256, 0, stream>>>(Wmt, Wphb, WcT, 256, 256, 256,
            nullptr, 1.f);

    // ---- GCN layer 1 (reassociated): AX = Adj@Xn, X1 = relu(AX@W1*nrm+b1) ---
    xt_k<<<512, 256, 0, stream>>>(g_poi, nrm, Xnt);
    agg1_k<<<512, 512, 0, stream>>>(adj8, Xnt, AX);
    mm256_k<true, true, 1, 1, true, true>
        <<<dim3(1, 400), 512, 0, stream>>>(AX, W1t, XPN, N_NODES, 256, 64,
            nrm, b1);
    // XPN = X1 (bf16)

    // ---- GCN layer 2: Yt = (X1@W2)^T * nrm[col], agg ----
    mm256_k<true, true, 2, 2, false, false>
        <<<dim3(400, 1), 512, 0, stream>>>(W2t, XPN, Yt, 256, N_NODES, 256,
            nrm, nullptr);
    agg256_k<<<512, 512, 0, stream>>>(adj8, Yt, XPN, nrm, b2, 0);
    // XPN = poi_nodes (bf16)

    pool_k<<<B_PAR, 256, 0, stream>>>(XPN, pool, poolb);

    // ---- med similarity (output 1) ----
    med_build_k<<<B_PAR, 256, 0, stream>>>(hrs, pool, medb);
    mm64_k<true, true, 0, false, false, true, 0>
        <<<dim3(8, 8), 256, 0, stream>>>(medb, medb, med_out, 512, 512, 512,
            nullptr, 0.5f);

    // ---- UniSimGraph GCN ----
    dinv_k<<<B_PAR, 256, 0, stream>>>(med_out, dinv);
    nadj_k<<<B_PAR, 256, 0, stream>>>(med_out, dinv, nadjb);
    mm64_k<true, true, 1, false, false, false, 0>
        <<<dim3(8, 4), 256, 0, stream>>>(Whgt, hrsb, Tcatt, 256, 512, 256,
            nullptr, 1.f);
    mm64_k<true, true, 1, false, false, false, 0>
        <<<dim3(8, 4), 256, 0, stream>>>(Wpgt, poolb, Tcatt + (size_t)256 * 512,
            256, 512, 256, nullptr, 1.f);
    mm64_k<true, true, 0, false, true, false, 0>
        <<<dim3(8, 8), 256, 0, stream>>>(nadjb, Tcatt, hpagg, 512, 512, 512,
            nullptr, 1.f);

    // ---- GAT poi2img (pp never materialized) ----
    gat_poi2img_k<<<B_PAR, 256, 0, stream>>>(XPN, wu, er, q);
    // p2i = (1/3) qPN @ WpG + bgg
    mm64_k<false, true, 0, true, false, false, 0>
        <<<dim3(4, 8), 256, 0, stream>>>(q, WpG, p2i, 512, 256, 768,
            bgg, 1.f / 3.f);

    // ---- img2poi pooled: i2p = hrs @ Wc + bc ----
    mm64_k<true, true, 0, true, false, false, 0>
        <<<dim3(4, 8), 256, 0, stream>>>(hrsb, WcT, i2p, 512, 256, 256,
            bc, 1.f);

    // ---- final fc ----
    final_k<<<24, 256, 0, stream>>>(i2p, hpagg, p2i, Wfc, bfc, out);
}

// Round 8
// 428.232 us; speedup vs baseline: 1.1663x; 1.1663x over previous
//
#include <hip/hip_runtime.h>
#include <hip/hip_bf16.h>
#include <math.h>

// ---------------------------------------------------------------------------
// NGLU: B=512 parcels x P=200 poi nodes. N=102400, E=1638400, HID=256.
// Round 8: wave-parallel GAT precomputes. The old single-block uv_k was 78 us
// of serial dot products on one CU (0.04% occupancy) sitting on the stream
// critical path; replaced by uv1_k/uv2_k/er2_k (one 64-lane wave per
// 256-length dot, float4 loads, shfl reduce). Rest unchanged from round 7.
// ---------------------------------------------------------------------------

#define N_NODES 102400
#define B_PAR   512
#define P_NODES 200
#define E_EDGES 1638400
#define HIDF    256

typedef __attribute__((ext_vector_type(8))) short bf16x8;
typedef __attribute__((ext_vector_type(4))) float f32x4;

__device__ __forceinline__ unsigned short f2bf(float x) {
    unsigned u = __builtin_bit_cast(unsigned, x);
    u += 0x7fffu + ((u >> 16) & 1u);               // RNE (finite data only)
    return (unsigned short)(u >> 16);
}
__device__ __forceinline__ float bf2f(unsigned short h) {
    return __builtin_bit_cast(float, (unsigned)h << 16);
}
// LDS tile [rows][64 k] bf16 = 128B/row; 16B-chunk XOR swizzle.
__device__ __forceinline__ int lds_off(int row, int kbyte) {
    return row * 128 + ((((kbyte >> 4) ^ (row & 7)) << 4) | (kbyte & 15));
}
template<bool BF16SRC>
__device__ __forceinline__ bf16x8 load_row8(const void* p, size_t elemoff) {
    if constexpr (BF16SRC) {
        return *(const bf16x8*)((const unsigned short*)p + elemoff);
    } else {
        const float* ap = (const float*)p + elemoff;
        float4 lo = *(const float4*)ap;
        float4 hi = *(const float4*)(ap + 4);
        union { bf16x8 v; unsigned short u[8]; } pk;
        pk.u[0] = f2bf(lo.x); pk.u[1] = f2bf(lo.y);
        pk.u[2] = f2bf(lo.z); pk.u[3] = f2bf(lo.w);
        pk.u[4] = f2bf(hi.x); pk.u[5] = f2bf(hi.y);
        pk.u[6] = f2bf(hi.z); pk.u[7] = f2bf(hi.w);
        return pk.v;
    }
}
__device__ __forceinline__ bf16x8 u8x8_to_bf16(uint2 w) {
    union { bf16x8 v; unsigned short u[8]; } r;
#pragma unroll
    for (int b = 0; b < 4; ++b) {
        r.u[b]     = (unsigned short)(__builtin_bit_cast(unsigned,
                        (float)((w.x >> (8 * b)) & 255u)) >> 16);   // exact: ints<256
        r.u[4 + b] = (unsigned short)(__builtin_bit_cast(unsigned,
                        (float)((w.y >> (8 * b)) & 255u)) >> 16);
    }
    return r.v;
}

// --------------------- 256x256-tile 8-wave MFMA GEMM ------------------------
// D[M,Nc] = A[M,K] @ B[Nc,K]^T  (row-major [m][k] / [n][k] operands)
// OMODE: 0=f32 [M][Nc], 1=bf16 [M][Nc], 2=bf16 parcel-transposed
//        (row=f, col=g -> Yt[g/200][f][g%200] of [512][256][256]).
// SCMODE: 0 none, 1 scale[row], 2 scale[col].
template<bool ABF16, bool BBF16, int OMODE, int SCMODE, bool BIASF, bool RELUF>
__global__ __launch_bounds__(512, 2) void mm256_k(
    const void* __restrict__ Ain, const void* __restrict__ Bin,
    void* __restrict__ Cout, int M, int Nc, int K,
    const float* __restrict__ scale, const float* __restrict__ bias)
{
    __shared__ bf16x8 smem_v[4096];                 // 64 KiB
    unsigned char* Asm = (unsigned char*)smem_v;
    unsigned char* Bsm = Asm + 32768;

    const int tid  = threadIdx.x;
    const int m0   = blockIdx.y * 256;
    const int n0   = blockIdx.x * 256;
    const int sr   = tid >> 3, sc = tid & 7;
    const int lane = tid & 63;
    const int wave = tid >> 6;
    const int wm   = wave >> 2, wn = wave & 3;      // wave tile: 128m x 64n
    const int frow = lane & 15;
    const int fko  = (lane >> 4) << 4;

    f32x4 acc[8][4];
    const f32x4 fz = {0.f, 0.f, 0.f, 0.f};
#pragma unroll
    for (int i = 0; i < 8; ++i)
#pragma unroll
        for (int j = 0; j < 4; ++j) acc[i][j] = fz;

    bf16x8 areg[4], breg[4];
    auto load_tiles = [&](int k0) {
#pragma unroll
        for (int i = 0; i < 4; ++i) {
            int row = sr + 64 * i;
            areg[i] = load_row8<ABF16>(Ain, (size_t)(m0 + row) * K + k0 + sc * 8);
            breg[i] = load_row8<BBF16>(Bin, (size_t)(n0 + row) * K + k0 + sc * 8);
        }
    };

    load_tiles(0);
    for (int k0 = 0; k0 < K; k0 += 64) {
        __syncthreads();
#pragma unroll
        for (int i = 0; i < 4; ++i) {
            *(bf16x8*)(Asm + lds_off(sr + 64 * i, sc * 16)) = areg[i];
            *(bf16x8*)(Bsm + lds_off(sr + 64 * i, sc * 16)) = breg[i];
        }
        __syncthreads();
        if (k0 + 64 < K) load_tiles(k0 + 64);
#pragma unroll
        for (int ks = 0; ks < 2; ++ks) {
            const int kb = ks * 64 + fko;
            bf16x8 bfr[4];
#pragma unroll
            for (int t = 0; t < 4; ++t)
                bfr[t] = *(const bf16x8*)(Bsm + lds_off(wn * 64 + t * 16 + frow, kb));
#pragma unroll
            for (int mi = 0; mi < 8; ++mi) {
                bf16x8 af = *(const bf16x8*)(Asm + lds_off(wm * 128 + mi * 16 + frow, kb));
#pragma unroll
                for (int ni = 0; ni < 4; ++ni)
                    acc[mi][ni] = __builtin_amdgcn_mfma_f32_16x16x32_bf16(
                        af, bfr[ni], acc[mi][ni], 0, 0, 0);
            }
        }
    }

    const int r4 = (lane >> 4) << 2;                // C/D: col=l&15, row=(l>>4)*4+j
#pragma unroll
    for (int mi = 0; mi < 8; ++mi) {
#pragma unroll
        for (int ni = 0; ni < 4; ++ni) {
            int col = n0 + wn * 64 + ni * 16 + frow;
#pragma unroll
            for (int j = 0; j < 4; ++j) {
                int row = m0 + wm * 128 + mi * 16 + r4 + j;
                float v = acc[mi][ni][j];
                if (SCMODE == 1) v *= scale[row];
                if (SCMODE == 2) v *= scale[col];
                if (BIASF)       v += bias[col];
                if (RELUF)       v = fmaxf(v, 0.f);
                if (OMODE == 0) {
                    ((float*)Cout)[(size_t)row * Nc + col] = v;
                } else if (OMODE == 1) {
                    ((unsigned short*)Cout)[(size_t)row * Nc + col] = f2bf(v);
                } else {
                    int p = col / 200, r = col - p * 200;
                    ((unsigned short*)Cout)[((size_t)p * 256 + row) * 256 + r] = f2bf(v);
                }
            }
        }
    }
}

// ------------- GCN aggregation L2: one block per parcel, 256x256 ------------
__global__ __launch_bounds__(512, 2) void agg256_k(
    const unsigned char* __restrict__ Adj, const unsigned short* __restrict__ Yt,
    unsigned short* __restrict__ Outb, const float* __restrict__ nrm,
    const float* __restrict__ bias, int relu)
{
    __shared__ bf16x8 smem_v[4096];
    unsigned char* Asm = (unsigned char*)smem_v;
    unsigned char* Bsm = Asm + 32768;

    const int tid  = threadIdx.x;
    const int p    = blockIdx.x;
    const int sr   = tid >> 3, sc = tid & 7;
    const int lane = tid & 63;
    const int wave = tid >> 6;
    const int wm   = wave >> 2, wn = wave & 3;
    const int frow = lane & 15;
    const int fko  = (lane >> 4) << 4;
    const size_t abase = (size_t)p * 65536;
    const size_t ybase = (size_t)p * 65536;

    f32x4 acc[8][4];
    const f32x4 fz = {0.f, 0.f, 0.f, 0.f};
#pragma unroll
    for (int i = 0; i < 8; ++i)
#pragma unroll
        for (int j = 0; j < 4; ++j) acc[i][j] = fz;

    uint2  awreg[4];
    bf16x8 breg[4];
    auto load_tiles = [&](int k0) {
#pragma unroll
        for (int i = 0; i < 4; ++i) {
            int row = sr + 64 * i;
            awreg[i] = *(const uint2*)(Adj + abase + (size_t)row * 256 + k0 + sc * 8);
            breg[i]  = *(const bf16x8*)(Yt + ybase + (size_t)row * 256 + k0 + sc * 8);
        }
    };

    load_tiles(0);
#pragma unroll
    for (int t4 = 0; t4 < 4; ++t4) {
        __syncthreads();
#pragma unroll
        for (int i = 0; i < 4; ++i) {
            *(bf16x8*)(Asm + lds_off(sr + 64 * i, sc * 16)) = u8x8_to_bf16(awreg[i]);
            *(bf16x8*)(Bsm + lds_off(sr + 64 * i, sc * 16)) = breg[i];
        }
        __syncthreads();
        if (t4 < 3) load_tiles((t4 + 1) * 64);
#pragma unroll
        for (int ks = 0; ks < 2; ++ks) {
            const int kb = ks * 64 + fko;
            bf16x8 bfr[4];
#pragma unroll
            for (int t = 0; t < 4; ++t)
                bfr[t] = *(const bf16x8*)(Bsm + lds_off(wn * 64 + t * 16 + frow, kb));
#pragma unroll
            for (int mi = 0; mi < 8; ++mi) {
                bf16x8 af = *(const bf16x8*)(Asm + lds_off(wm * 128 + mi * 16 + frow, kb));
#pragma unroll
                for (int ni = 0; ni < 4; ++ni)
                    acc[mi][ni] = __builtin_amdgcn_mfma_f32_16x16x32_bf16(
                        af, bfr[ni], acc[mi][ni], 0, 0, 0);
            }
        }
    }

    const int r4 = (lane >> 4) << 2;
#pragma unroll
    for (int mi = 0; mi < 8; ++mi) {
#pragma unroll
        for (int ni = 0; ni < 4; ++ni) {
            int col = wn * 64 + ni * 16 + frow;
#pragma unroll
            for (int j = 0; j < 4; ++j) {
                int d = wm * 128 + mi * 16 + r4 + j;
                if (d < 200) {
                    int g = p * 200 + d;
                    float v = acc[mi][ni][j] * nrm[g] + bias[col];
                    if (relu) v = fmaxf(v, 0.f);
                    Outb[(size_t)g * 256 + col] = f2bf(v);
                }
            }
        }
    }
}

// --------- GCN aggregation L1 (reassociated): AX = Adj @ Xnt^T --------------
__global__ __launch_bounds__(512) void agg1_k(
    const unsigned char* __restrict__ Adj, const unsigned short* __restrict__ Xnt,
    unsigned short* __restrict__ AX)
{
    __shared__ bf16x8 smem_v[2560];                 // 40 KiB: A 32K + B 8K
    unsigned char* Asm = (unsigned char*)smem_v;
    unsigned char* Bsm = Asm + 32768;

    const int tid  = threadIdx.x;
    const int p    = blockIdx.x;
    const int arow = tid >> 1, ah = tid & 1;
    const int brow = tid >> 3, sc = tid & 7;
    const int lane = tid & 63;
    const int wave = tid >> 6;
    const int frow = lane & 15;
    const int fko  = (lane >> 4) << 4;
    const size_t abase = (size_t)p * 65536;
    const size_t xbase = (size_t)p * 16384;

    f32x4 acc[2][4];
    const f32x4 fz = {0.f, 0.f, 0.f, 0.f};
#pragma unroll
    for (int i = 0; i < 2; ++i)
#pragma unroll
        for (int j = 0; j < 4; ++j) acc[i][j] = fz;

    uint4  aw[2];
    bf16x8 bg;
    auto load_tiles = [&](int k0) {
        const uint4* ap = (const uint4*)(Adj + abase + (size_t)arow * 256 + k0 + ah * 32);
        aw[0] = ap[0];
        aw[1] = ap[1];
        bg = *(const bf16x8*)(Xnt + xbase + (size_t)brow * 256 + k0 + sc * 8);
    };

    load_tiles(0);
#pragma unroll
    for (int t4 = 0; t4 < 4; ++t4) {
        __syncthreads();
        {
            uint2 l0 = {aw[0].x, aw[0].y}, h0 = {aw[0].z, aw[0].w};
            uint2 l1 = {aw[1].x, aw[1].y}, h1 = {aw[1].z, aw[1].w};
            int base = ah * 64;
            *(bf16x8*)(Asm + lds_off(arow, base +  0)) = u8x8_to_bf16(l0);
            *(bf16x8*)(Asm + lds_off(arow, base + 16)) = u8x8_to_bf16(h0);
            *(bf16x8*)(Asm + lds_off(arow, base + 32)) = u8x8_to_bf16(l1);
            *(bf16x8*)(Asm + lds_off(arow, base + 48)) = u8x8_to_bf16(h1);
            *(bf16x8*)(Bsm + lds_off(brow, sc * 16)) = bg;
        }
        __syncthreads();
        if (t4 < 3) load_tiles((t4 + 1) * 64);
#pragma unroll
        for (int ks = 0; ks < 2; ++ks) {
            const int kb = ks * 64 + fko;
            bf16x8 bfr[4];
#pragma unroll
            for (int t = 0; t < 4; ++t)
                bfr[t] = *(const bf16x8*)(Bsm + lds_off(t * 16 + frow, kb));
#pragma unroll
            for (int mi = 0; mi < 2; ++mi) {
                bf16x8 af = *(const bf16x8*)(Asm + lds_off(wave * 32 + mi * 16 + frow, kb));
#pragma unroll
                for (int ni = 0; ni < 4; ++ni)
                    acc[mi][ni] = __builtin_amdgcn_mfma_f32_16x16x32_bf16(
                        af, bfr[ni], acc[mi][ni], 0, 0, 0);
            }
        }
    }

    const int r4 = (lane >> 4) << 2;
#pragma unroll
    for (int mi = 0; mi < 2; ++mi) {
#pragma unroll
        for (int ni = 0; ni < 4; ++ni) {
            int col = ni * 16 + frow;
#pragma unroll
            for (int j = 0; j < 4; ++j) {
                int d = wave * 32 + mi * 16 + r4 + j;
                if (d < 200)
                    AX[((size_t)(p * 200 + d)) * 64 + col] = f2bf(acc[mi][ni][j]);
            }
        }
    }
}

// -------- Xnt[p][k][s] = g_poi[p*200+s][k] * nrm[p*200+s] (pad s>=200) -------
__global__ __launch_bounds__(256) void xt_k(const float* __restrict__ gp,
                                            const float* __restrict__ nrm,
                                            unsigned short* __restrict__ Xnt)
{
    __shared__ unsigned short lsh[64][264];
    const int p = blockIdx.x, tid = threadIdx.x;
    for (int idx = tid; idx < 256 * 16; idx += 256) {
        int s = idx >> 4, kc = idx & 15;
        float4 v = {0.f, 0.f, 0.f, 0.f};
        float nr = 0.f;
        if (s < 200) {
            v = *(const float4*)(gp + ((size_t)(p * 200 + s)) * 64 + kc * 4);
            nr = nrm[p * 200 + s];
        }
        lsh[kc * 4 + 0][s] = f2bf(v.x * nr);
        lsh[kc * 4 + 1][s] = f2bf(v.y * nr);
        lsh[kc * 4 + 2][s] = f2bf(v.z * nr);
        lsh[kc * 4 + 3][s] = f2bf(v.w * nr);
    }
    __syncthreads();
    for (int idx = tid; idx < 64 * 32; idx += 256) {
        int k = idx >> 5, ch = idx & 31;
        uint4 o = *(const uint4*)(&lsh[k][ch * 8]);
        *(uint4*)(Xnt + (size_t)p * 16384 + k * 256 + ch * 8) = o;
    }
}

// ----------------------- 64x64 MFMA GEMM (small shapes) ---------------------
template<bool ABF16, bool BBF16, int OMODE, bool BIASF, bool RELUF,
         bool MEDOUT, int KCHUNK>
__global__ __launch_bounds__(256) void mm64_k(
    const void* __restrict__ Ain, const void* __restrict__ Bin,
    void* __restrict__ Cout, int M, int Nc, int K,
    const float* __restrict__ bias, float alpha)
{
    __shared__ bf16x8 smem_v[1024];                 // 16 KiB
    unsigned char* Asm = (unsigned char*)smem_v;
    unsigned char* Bsm = Asm + 8192;

    const int tid  = threadIdx.x;
    const int m0   = blockIdx.y * 64;
    const int n0   = blockIdx.x * 64;
    const int sr   = tid >> 3, sc = tid & 7;
    const int lane = tid & 63;
    const int wm   = (tid >> 7) & 1, wn = (tid >> 6) & 1;
    const int frow = lane & 15;
    const int fko  = (lane >> 4) << 4;

    int kbeg = 0, kend = K;
    float* Cf = (float*)Cout;
    if (KCHUNK > 0) {
        kbeg = blockIdx.z * KCHUNK; kend = kbeg + KCHUNK;
        Cf += (size_t)blockIdx.z * M * Nc;
    }

    f32x4 acc[2][2];
    const f32x4 fz = {0.f, 0.f, 0.f, 0.f};
#pragma unroll
    for (int i = 0; i < 2; ++i)
#pragma unroll
        for (int j = 0; j < 2; ++j) acc[i][j] = fz;

    bf16x8 areg[2], breg[2];
    auto load_tiles = [&](int k0) {
#pragma unroll
        for (int i = 0; i < 2; ++i) {
            int row = sr + 32 * i;
            areg[i] = load_row8<ABF16>(Ain, (size_t)(m0 + row) * K + k0 + sc * 8);
            breg[i] = load_row8<BBF16>(Bin, (size_t)(n0 + row) * K + k0 + sc * 8);
        }
    };

    load_tiles(kbeg);
    for (int k0 = kbeg; k0 < kend; k0 += 64) {
        __syncthreads();
#pragma unroll
        for (int i = 0; i < 2; ++i) {
            *(bf16x8*)(Asm + lds_off(sr + 32 * i, sc * 16)) = areg[i];
            *(bf16x8*)(Bsm + lds_off(sr + 32 * i, sc * 16)) = breg[i];
        }
        __syncthreads();
        if (k0 + 64 < kend) load_tiles(k0 + 64);
#pragma unroll
        for (int ks = 0; ks < 2; ++ks) {
            const int kb = ks * 64 + fko;
            bf16x8 af[2], bfr[2];
#pragma unroll
            for (int t = 0; t < 2; ++t)
                af[t] = *(const bf16x8*)(Asm + lds_off(wm * 32 + t * 16 + frow, kb));
#pragma unroll
            for (int t = 0; t < 2; ++t)
                bfr[t] = *(const bf16x8*)(Bsm + lds_off(wn * 32 + t * 16 + frow, kb));
#pragma unroll
            for (int mi = 0; mi < 2; ++mi)
#pragma unroll
                for (int ni = 0; ni < 2; ++ni)
                    acc[mi][ni] = __builtin_amdgcn_mfma_f32_16x16x32_bf16(
                        af[mi], bfr[ni], acc[mi][ni], 0, 0, 0);
        }
    }

    const int r4 = (lane >> 4) << 2;
#pragma unroll
    for (int mi = 0; mi < 2; ++mi) {
#pragma unroll
        for (int ni = 0; ni < 2; ++ni) {
            int col = n0 + wn * 32 + ni * 16 + frow;
#pragma unroll
            for (int j = 0; j < 4; ++j) {
                int row = m0 + wm * 32 + mi * 16 + r4 + j;
                float v = acc[mi][ni][j] * alpha;
                if (BIASF)  v += bias[col];
                if (RELUF)  v = fmaxf(v, 0.f);
                if (MEDOUT) v += 0.5f;
                if (OMODE == 0) {
                    Cf[(size_t)row * Nc + col] = v;
                } else {
                    ((unsigned short*)Cout)[(size_t)row * Nc + col] = f2bf(v);
                }
            }
        }
    }
}

// ------------------------- graph preprocessing -----------------------------
__global__ __launch_bounds__(256) void edge_diag_k(
    const int* __restrict__ esrc, const int* __restrict__ edst,
    unsigned char* __restrict__ A)
{
    int id = blockIdx.x * 256 + threadIdx.x;        // E + N = 1740800
    size_t bo;
    if (id < E_EDGES) {
        int s = esrc[id], d = edst[id];
        int p = d / 200;
        int dl = d - p * 200, sl = s - p * 200;
        bo = (((size_t)(p * 256 + dl)) << 8) + (unsigned)sl;
    } else {
        int i2 = id - E_EDGES;                      // < N
        int p = i2 / 200, d = i2 - p * 200;
        bo = (((size_t)(p * 256 + d)) << 8) + (unsigned)d;
    }
    atomicAdd((unsigned int*)(A + (bo & ~(size_t)3)), 1u << ((bo & 3) * 8));
}

__global__ __launch_bounds__(256) void norm2_k(const unsigned char* __restrict__ A,
                                               float* __restrict__ nrm)
{
    int g = blockIdx.x * 256 + threadIdx.x;
    int p = g / 200, d = g - p * 200;
    const uint4* row = (const uint4*)(A + (((size_t)(p * 256 + d)) << 8));
    unsigned s = 0;
#pragma unroll
    for (int i = 0; i < 16; ++i) {
        uint4 w = row[i];
        unsigned a = w.x, b = w.y, c = w.z, e = w.w;
        s += (a & 255) + ((a >> 8) & 255) + ((a >> 16) & 255) + (a >> 24);
        s += (b & 255) + ((b >> 8) & 255) + ((b >> 16) & 255) + (b >> 24);
        s += (c & 255) + ((c >> 8) & 255) + ((c >> 16) & 255) + (c >> 24);
        s += (e & 255) + ((e >> 8) & 255) + ((e >> 16) & 255) + (e >> 24);
    }
    nrm[g] = rsqrtf((float)s);                      // row-sum = in-deg + self
}

// ------------- all weight transposes/casts + img cast -----------------------
__global__ __launch_bounds__(256) void prep_k(
    const float* __restrict__ W1, const float* __restrict__ W2,
    const float* __restrict__ Whg,
    const float* __restrict__ Wpg, const float* __restrict__ Whrs,
    const float* __restrict__ Wgin, const float* __restrict__ Wgw,
    const float* __restrict__ Wph, const float* __restrict__ img,
    unsigned short* __restrict__ W1t, unsigned short* __restrict__ W2t,
    unsigned short* __restrict__ Whgt,
    unsigned short* __restrict__ Wpgt, unsigned short* __restrict__ Whrst,
    unsigned short* __restrict__ Wgint, unsigned short* __restrict__ Wmt,
    unsigned short* __restrict__ Wphb, unsigned short* __restrict__ imgb)
{
    int b = blockIdx.x, tid = threadIdx.x;
    if (b < 64) {                 // W1t [256][64]
        int id = b * 256 + tid; int n = id >> 6, k = id & 63;
        W1t[id] = f2bf(W1[(size_t)k * 256 + n]);
    } else if (b < 320) {         // W2t [256][256]
        int id = (b - 64) * 256 + tid; int n = id >> 8, k = id & 255;
        W2t[id] = f2bf(W2[(size_t)k * 256 + n]);
    } else if (b < 576) {         // Whgt
        int id = (b - 320) * 256 + tid; int n = id >> 8, k = id & 255;
        Whgt[id] = f2bf(Whg[(size_t)k * 256 + n]);
    } else if (b < 832) {         // Wpgt
        int id = (b - 576) * 256 + tid; int n = id >> 8, k = id & 255;
        Wpgt[id] = f2bf(Wpg[(size_t)k * 256 + n]);
    } else if (b < 2880) {        // Whrst [256][2048]
        int id = (b - 832) * 256 + tid; int n = id >> 11, k = id & 2047;
        Whrst[id] = f2bf(Whrs[(size_t)k * 256 + n]);
    } else if (b < 3648) {        // Wgint [256][768], k-order = h*256+t
        int id = (b - 2880) * 256 + tid; int j = id / 768, k2 = id - j * 768;
        int t = k2 & 255, h = k2 >> 8;
        Wgint[id] = f2bf(Wgin[(size_t)t * 768 + h * 256 + j]);
    } else if (b < 3904) {        // Wmt [256 j][256 t] = mean_h Wgw / (1+1e-9)
        int id = (b - 3648) * 256 + tid; int j = id >> 8, t = id & 255;
        const float c3 = (1.f / 3.f) * (1.f / (1.f + 1e-9f));
        float s = Wgw[(size_t)t * 768 + j] + Wgw[(size_t)t * 768 + 256 + j] +
                  Wgw[(size_t)t * 768 + 512 + j];
        Wmt[id] = f2bf(s * c3);
    } else if (b < 4160) {        // Wphb cast
        int id = (b - 3904) * 256 + tid;
        Wphb[id] = f2bf(Wph[id]);
    } else {                      // imgb cast [512][2048]
        int id = (b - 4160) * 256 + tid;
        imgb[id] = f2bf(img[id]);
    }
}

// --- WpG[j][(h,c)] = sum_t Wpp[c][t]*Wgin[t][h*256+j]; bgg[j] (bias fold) ----
__global__ __launch_bounds__(256) void wpg_k(
    const float* __restrict__ Wpp, const float* __restrict__ Wgin,
    const float* __restrict__ bpp,
    unsigned short* __restrict__ WpG, float* __restrict__ bgg)
{
    __shared__ float wsh[256];
    const int b = blockIdx.x, j = threadIdx.x;
    if (b < 768) {
        int h = b >> 8, c = b & 255;
        wsh[j] = Wpp[(size_t)c * 256 + j];
        __syncthreads();
        float acc = 0.f;
        for (int t = 0; t < 256; ++t)
            acc += wsh[t] * Wgin[(size_t)t * 768 + h * 256 + j];
        WpG[(size_t)j * 768 + h * 256 + c] = f2bf(acc);
    } else {
        float s = 0.f;
        for (int h = 0; h < 3; ++h)
            for (int t = 0; t < 256; ++t)
                s += bpp[t] * Wgin[(size_t)t * 768 + h * 256 + j];
        bgg[j] = s * (1.f / 3.f);
    }
}

// --------------------------- hrs split-K reduce -----------------------------
__global__ __launch_bounds__(256) void hrs_reduce_k(
    const float* __restrict__ part, const float* __restrict__ bhrs,
    float* __restrict__ hrs, unsigned short* __restrict__ hrsb)
{
    int id = blockIdx.x * 256 + threadIdx.x;        // 131072
    float s = bhrs[id & 255];
#pragma unroll
    for (int z = 0; z < 8; ++z) s += part[(size_t)z * 131072 + id];
    hrs[id] = s;
    hrsb[id] = f2bf(s);
}

// ------------------------------ pooling (vectorized) ------------------------
__global__ __launch_bounds__(256) void pool_k(const unsigned short* __restrict__ X,
                                              float* __restrict__ Pl,
                                              unsigned short* __restrict__ Plb)
{
    __shared__ float sh[2048];
    const int b = blockIdx.x, tid = threadIdx.x;
    const int cg = tid & 31, rg = tid >> 5;
    const size_t base = (size_t)b * P_NODES * HIDF + cg * 8;
    float acc[8] = {};
    for (int n = rg; n < P_NODES; n += 8) {
        union { uint4 q; unsigned short u[8]; } v;
        v.q = *(const uint4*)(X + base + (size_t)n * HIDF);
#pragma unroll
        for (int j = 0; j < 8; ++j) acc[j] += bf2f(v.u[j]);
    }
#pragma unroll
    for (int j = 0; j < 8; ++j) sh[rg * 256 + cg * 8 + j] = acc[j];
    __syncthreads();
    float s = 0.f;
#pragma unroll
    for (int r = 0; r < 8; ++r) s += sh[r * 256 + tid];
    s *= (1.f / 200.f);
    Pl[(size_t)b * 256 + tid] = s;
    Plb[(size_t)b * 256 + tid] = f2bf(s);
}

// ------------------- med = rownorm(concat(hrs, pool)) -----------------------
__global__ __launch_bounds__(256) void med_build_k(
    const float* __restrict__ hrs, const float* __restrict__ pool,
    unsigned short* __restrict__ medb)
{
    __shared__ float red[256];
    int b = blockIdx.x, f = threadIdx.x;
    float v0 = hrs[(size_t)b * 256 + f];
    float v1 = pool[(size_t)b * 256 + f];
    red[f] = v0 * v0 + v1 * v1;
    __syncthreads();
    for (int s = 128; s > 0; s >>= 1) {
        if (f < s) red[f] += red[f + s];
        __syncthreads();
    }
    float inv = rsqrtf(red[0]);
    medb[(size_t)b * 512 + f]       = f2bf(v0 * inv);
    medb[(size_t)b * 512 + 256 + f] = f2bf(v1 * inv);
}

// ---------------------- thresholded-similarity GCN --------------------------
__global__ __launch_bounds__(256) void dinv_k(const float* __restrict__ mo,
                                              float* __restrict__ dinv)
{
    __shared__ int red[256];
    int i = blockIdx.x, t = threadIdx.x;
    int c = 0;
    for (int j = t; j < 512; j += 256) c += (mo[(size_t)i * 512 + j] >= 0.9f) ? 1 : 0;
    red[t] = c; __syncthreads();
    for (int s = 128; s > 0; s >>= 1) {
        if (t < s) red[t] += red[t + s];
        __syncthreads();
    }
    if (t == 0) dinv[i] = rsqrtf((float)red[0]);
}

__global__ __launch_bounds__(256) void nadj_k(const float* __restrict__ mo,
                                              const float* __restrict__ dinv,
                                              unsigned short* __restrict__ nadjb)
{
    int i = blockIdx.x, t = threadIdx.x;
    float di = dinv[i];
    for (int j = t; j < 512; j += 256) {
        float a = (mo[(size_t)i * 512 + j] >= 0.9f || j == i) ? 1.f : 0.f;
        nadjb[(size_t)i * 512 + j] = f2bf(a * di * dinv[j]);
    }
}

// ---------------- GAT precomputes: wave-parallel dot products ---------------
// uv1: u2[k*3+h] = Wgin[k][h*256:].al[h], v2 same with ar. 768 tasks.
__global__ __launch_bounds__(256) void uv1_k(
    const float* __restrict__ Wgin, const float* __restrict__ al,
    const float* __restrict__ ar,
    float* __restrict__ u2, float* __restrict__ v2)
{
    const int wave = threadIdx.x >> 6, lane = threadIdx.x & 63;
    const int task = blockIdx.x * 4 + wave;         // < 768
    const int k = task / 3, h = task - k * 3;
    float4 w = *(const float4*)(Wgin + (size_t)k * 768 + h * 256 + lane * 4);
    float4 a = *(const float4*)(al + h * 256 + lane * 4);
    float4 r = *(const float4*)(ar + h * 256 + lane * 4);
    float su = w.x * a.x + w.y * a.y + w.z * a.z + w.w * a.w;
    float sv = w.x * r.x + w.y * r.y + w.z * r.z + w.w * r.w;
#pragma unroll
    for (int o = 32; o > 0; o >>= 1) {
        su += __shfl_xor(su, o);
        sv += __shfl_xor(sv, o);
    }
    if (lane == 0) { u2[task] = su; v2[task] = sv; }
}

// uv2: vv2[k,h]=Wph[k].v2[:,h]; wu[k,h]=Wpp[k].u2[:,h]; bc[k]=bph.Wmt[k];
//      erb[h]=bph.v2[:,h]; eb0[h]=bpp.u2[:,h].  1798 tasks.
__global__ __launch_bounds__(256) void uv2_k(
    const float* __restrict__ Wph, const float* __restrict__ Wpp,
    const float* __restrict__ bph, const float* __restrict__ bpp,
    const unsigned short* __restrict__ Wmt,
    const float* __restrict__ u2, const float* __restrict__ v2,
    float* __restrict__ vv2, float* __restrict__ wu,
    float* __restrict__ bc, float* __restrict__ erb, float* __restrict__ eb0)
{
    __shared__ float ush[768], vsh[768];
    const int tid = threadIdx.x;
    for (int i = tid; i < 768; i += 256) { ush[i] = u2[i]; vsh[i] = v2[i]; }
    __syncthreads();
    const int wave = tid >> 6, lane = tid & 63;
    const int task = blockIdx.x * 4 + wave;
    float s = 0.f;
    if (task < 1536) {
        int t2 = task < 768 ? task : task - 768;
        int k = t2 / 3, h = t2 - k * 3;
        const float* W = task < 768 ? Wph : Wpp;
        const float* vec = task < 768 ? vsh : ush;
        float4 w = *(const float4*)(W + (size_t)k * 256 + lane * 4);
        s = w.x * vec[(lane * 4 + 0) * 3 + h] + w.y * vec[(lane * 4 + 1) * 3 + h]
          + w.z * vec[(lane * 4 + 2) * 3 + h] + w.w * vec[(lane * 4 + 3) * 3 + h];
#pragma unroll
        for (int o = 32; o > 0; o >>= 1) s += __shfl_xor(s, o);
        if (lane == 0) { if (task < 768) vv2[t2] = s; else wu[t2] = s; }
    } else if (task < 1792) {
        int k = task - 1536;
        float4 b4 = *(const float4*)(bph + lane * 4);
        const unsigned short* wm = Wmt + (size_t)k * 256 + lane * 4;
        s = b4.x * bf2f(wm[0]) + b4.y * bf2f(wm[1])
          + b4.z * bf2f(wm[2]) + b4.w * bf2f(wm[3]);
#pragma unroll
        for (int o = 32; o > 0; o >>= 1) s += __shfl_xor(s, o);
        if (lane == 0) bc[k] = s;
    } else if (task < 1798) {
        int t2 = task - 1792;
        int h = t2 % 3;
        bool second = t2 >= 3;
        const float* bias = second ? bpp : bph;
        const float* vec  = second ? ush : vsh;
        float4 b4 = *(const float4*)(bias + lane * 4);
        s = b4.x * vec[(lane * 4 + 0) * 3 + h] + b4.y * vec[(lane * 4 + 1) * 3 + h]
          + b4.z * vec[(lane * 4 + 2) * 3 + h] + b4.w * vec[(lane * 4 + 3) * 3 + h];
#pragma unroll
        for (int o = 32; o > 0; o >>= 1) s += __shfl_xor(s, o);
        if (lane == 0) { if (second) eb0[h] = s; else erb[h] = s; }
    }
}

// er2: er[b*3+h] = erb[h] + eb0[h] + hrs[b].vv2[:,h].  1536 tasks.
__global__ __launch_bounds__(256) void er2_k(
    const float* __restrict__ hrs, const float* __restrict__ vv2,
    const float* __restrict__ erb, const float* __restrict__ eb0,
    float* __restrict__ er)
{
    __shared__ float vsh[768];
    const int tid = threadIdx.x;
    for (int i = tid; i < 768; i += 256) vsh[i] = vv2[i];
    __syncthreads();
    const int wave = tid >> 6, lane = tid & 63;
    const int task = blockIdx.x * 4 + wave;         // < 1536
    const int b = task / 3, h = task - b * 3;
    float4 hv = *(const float4*)(hrs + (size_t)b * 256 + lane * 4);
    float s = hv.x * vsh[(lane * 4 + 0) * 3 + h] + hv.y * vsh[(lane * 4 + 1) * 3 + h]
            + hv.z * vsh[(lane * 4 + 2) * 3 + h] + hv.w * vsh[(lane * 4 + 3) * 3 + h];
#pragma unroll
    for (int o = 32; o > 0; o >>= 1) s += __shfl_xor(s, o);
    if (lane == 0) er[task] = erb[h] + eb0[h] + s;
}

// Per-parcel: el = PN@wu, e = leaky(el+er), softmax over 200 nodes/head,
// qPN[b,h,:] = sum_n alpha[n,h] * PN[n,:]
__global__ __launch_bounds__(256) void gat_poi2img_k(
    const unsigned short* __restrict__ PN, const float* __restrict__ wu,
    const float* __restrict__ er, float* __restrict__ q)
{
    __shared__ float esh[600];
    __shared__ float ash[600];
    __shared__ float ush[768];
    __shared__ float mz[8];
    const int p = blockIdx.x, tid = threadIdx.x;
    const size_t base = (size_t)p * P_NODES;

    for (int i = tid; i < 768; i += 256) ush[i] = wu[i];
    __syncthreads();

    for (int it = tid; it < 600; it += 256) {
        int n = it / 3, h = it % 3;
        const unsigned short* row = PN + (base + n) * HIDF;
        float s = 0.f;
        for (int k = 0; k < 256; k += 8) {
            union { uint4 qv; unsigned short us[8]; } w;
            w.qv = *(const uint4*)(row + k);
#pragma unroll
            for (int j = 0; j < 8; ++j) s += bf2f(w.us[j]) * ush[(k + j) * 3 + h];
        }
        s += er[p * 3 + h];
        esh[it] = s > 0.f ? s : 0.2f * s;
    }
    __syncthreads();

    int wave = tid >> 6, lane = tid & 63;
    if (wave < 3) {
        float mx = -1e30f;
        for (int n = lane; n < P_NODES; n += 64) mx = fmaxf(mx, esh[n * 3 + wave]);
        for (int o = 32; o > 0; o >>= 1) mx = fmaxf(mx, __shfl_xor(mx, o));
        float sm = 0.f;
        for (int n = lane; n < P_NODES; n += 64) sm += expf(esh[n * 3 + wave] - mx);
        for (int o = 32; o > 0; o >>= 1) sm += __shfl_xor(sm, o);
        if (lane == 0) { mz[wave] = mx; mz[4 + wave] = sm; }
    }
    __syncthreads();

    for (int it = tid; it < 600; it += 256) {
        int h = it % 3;
        ash[it] = expf(esh[it] - mz[h]) / (mz[4 + h] + 1e-9f);
    }
    __syncthreads();

    float a0 = 0.f, a1 = 0.f, a2 = 0.f;
    for (int n = 0; n < P_NODES; ++n) {
        float vv = bf2f(PN[(base + n) * HIDF + tid]);
        a0 += ash[n * 3 + 0] * vv;
        a1 += ash[n * 3 + 1] * vv;
        a2 += ash[n * 3 + 2] * vv;
    }
    q[((size_t)p * 3 + 0) * 256 + tid] = a0;
    q[((size_t)p * 3 + 1) * 256 + tid] = a1;
    q[((size_t)p * 3 + 2) * 256 + tid] = a2;
}

// --------------------------- final projection -------------------------------
__global__ __launch_bounds__(256) void final_k(
    const float* __restrict__ i2p, const float* __restrict__ hpagg,
    const float* __restrict__ p2i,
    const float* __restrict__ Wfc, const float* __restrict__ bfc,
    float* __restrict__ out)
{
    int id = blockIdx.x * 256 + threadIdx.x;
    if (id >= B_PAR * 12) return;
    int b = id / 12, o = id % 12;
    float acc = bfc[o];
    const float* s0 = i2p + (size_t)b * 256;          // img2poi_pooled
    const float* s1 = hpagg + (size_t)b * 512 + 256;  // poi_agg
    const float* s2 = p2i + (size_t)b * 256;          // poi2img
    const float* s3 = hpagg + (size_t)b * 512;        // hrs_agg
    for (int k = 0; k < 256; ++k) {
        acc += s0[k] * Wfc[(size_t)(0 * 256 + k) * 12 + o];
        acc += s1[k] * Wfc[(size_t)(1 * 256 + k) * 12 + o];
        acc += s2[k] * Wfc[(size_t)(2 * 256 + k) * 12 + o];
        acc += s3[k] * Wfc[(size_t)(3 * 256 + k) * 12 + o];
    }
    out[id] = acc;
}

// ---------------------------------------------------------------------------
extern "C" void kernel_launch(void* const* d_in, const int* in_sizes, int n_in,
                              void* d_out, int out_size, void* d_ws, size_t ws_size,
                              hipStream_t stream)
{
    const float* g_poi = (const float*)d_in[0];
    const float* img   = (const float*)d_in[1];
    const int*   esrc  = (const int*)d_in[2];
    const int*   edst  = (const int*)d_in[3];
    const float* W1    = (const float*)d_in[4];
    const float* b1    = (const float*)d_in[5];
    const float* W2    = (const float*)d_in[6];
    const float* b2    = (const float*)d_in[7];
    const float* Whrs  = (const float*)d_in[8];
    const float* bhrs  = (const float*)d_in[9];
    const float* Wph   = (const float*)d_in[10];
    const float* bph   = (const float*)d_in[11];
    const float* Wpp   = (const float*)d_in[12];
    const float* bpp   = (const float*)d_in[13];
    const float* Wgin  = (const float*)d_in[14];
    const float* alin  = (const float*)d_in[15];
    const float* arin  = (const float*)d_in[16];
    const float* Wgw   = (const float*)d_in[17];
    // d_in[18]/d_in[19] (al_with/ar_with) numerically dead: each poi node has
    // exactly one incoming parcel edge -> edge-softmax weight = 1/(1+1e-9).
    const float* Whg   = (const float*)d_in[20];
    const float* Wpg   = (const float*)d_in[21];
    const float* Wfc   = (const float*)d_in[22];
    const float* bfc   = (const float*)d_in[23];

    float* out     = (float*)d_out;
    float* med_out = out + B_PAR * 12;

    char* ws = (char*)d_ws;
    size_t off = 0;
    auto take = [&](size_t bytes) { void* pv = ws + off; off += (bytes + 255) & ~(size_t)255; return pv; };

    unsigned char*  adj8 = (unsigned char*)take((size_t)B_PAR * 256 * 256);     // 33.6MB
    unsigned short* Yt   = (unsigned short*)take((size_t)B_PAR * 256 * 256 * 2);// 67.1MB
    unsigned short* Xnt  = Yt;                      // [512][64][256], dead before Yt written
    unsigned short* XPN  = (unsigned short*)take((size_t)N_NODES * 256 * 2);    // 52.4MB
    unsigned short* AX   = (unsigned short*)take((size_t)N_NODES * 64 * 2);     // 13.1MB
    float*          part = (float*)take((size_t)8 * 512 * 256 * 4);             // 4.2MB

    unsigned short* W1t   = (unsigned short*)take(256 * 64 * 2);
    unsigned short* W2t   = (unsigned short*)take(256 * 256 * 2);
    unsigned short* Whgt  = (unsigned short*)take(256 * 256 * 2);
    unsigned short* Wpgt  = (unsigned short*)take(256 * 256 * 2);
    unsigned short* Whrst = (unsigned short*)take((size_t)256 * 2048 * 2);
    unsigned short* Wgint = (unsigned short*)take((size_t)256 * 768 * 2);
    unsigned short* Wmt   = (unsigned short*)take(256 * 256 * 2);
    unsigned short* Wphb  = (unsigned short*)take(256 * 256 * 2);
    unsigned short* WcT   = (unsigned short*)take(256 * 256 * 2);
    unsigned short* WpG   = (unsigned short*)take((size_t)256 * 768 * 2);
    unsigned short* imgb  = (unsigned short*)take((size_t)512 * 2048 * 2);
    unsigned short* hrsb  = (unsigned short*)take((size_t)B_PAR * 256 * 2);
    unsigned short* poolb = (unsigned short*)take((size_t)B_PAR * 256 * 2);
    unsigned short* medb  = (unsigned short*)take((size_t)B_PAR * 512 * 2);
    unsigned short* nadjb = (unsigned short*)take((size_t)B_PAR * 512 * 2);
    unsigned short* Tcatt = (unsigned short*)take((size_t)512 * 512 * 2);
    float* nrm   = (float*)take((size_t)N_NODES * 4);
    float* hrs   = (float*)take((size_t)B_PAR * 256 * 4);
    float* pool  = (float*)take((size_t)B_PAR * 256 * 4);
    float* dinv  = (float*)take((size_t)B_PAR * 4);
    float* hpagg = (float*)take((size_t)B_PAR * 512 * 4);
    float* u2    = (float*)take(768 * 4);
    float* v2    = (float*)take(768 * 4);
    float* wu    = (float*)take(768 * 4);
    float* vv2   = (float*)take(768 * 4);
    float* erb   = (float*)take(16);
    float* eb0   = (float*)take(16);
    float* bc    = (float*)take(256 * 4);
    float* bgg   = (float*)take(256 * 4);
    float* er    = (float*)take((size_t)B_PAR * 3 * 4);
    float* q     = (float*)take((size_t)B_PAR * 768 * 4);
    float* p2i   = (float*)take((size_t)B_PAR * 256 * 4);
    float* i2p   = (float*)take((size_t)B_PAR * 256 * 4);
    (void)ws_size; (void)in_sizes; (void)n_in; (void)out_size;

    // ---- preprocessing ----
    hipMemsetAsync(adj8, 0, (size_t)B_PAR * 256 * 256, stream);
    prep_k<<<8256, 256, 0, stream>>>(W1, W2, Whg, Wpg, Whrs, Wgin, Wgw,
        Wph, img, W1t, W2t, Whgt, Wpgt, Whrst, Wgint, Wmt, Wphb, imgb);
    edge_diag_k<<<(E_EDGES + N_NODES) / 256, 256, 0, stream>>>(esrc, edst, adj8);
    norm2_k<<<N_NODES / 256, 256, 0, stream>>>(adj8, nrm);
    wpg_k<<<769, 256, 0, stream>>>(Wpp, Wgin, bpp, WpG, bgg);

    // ---- hrs encoder: split-K (8x256) 64-tile MFMA + reduce ----
    mm64_k<true, true, 0, false, false, false, 256>
        <<<dim3(4, 8, 8), 256, 0, stream>>>(imgb, Whrst, part, 512, 256, 2048,
            nullptr, 1.f);
    hrs_reduce_k<<<512, 256, 0, stream>>>(part, bhrs, hrs, hrsb);

    // ---- GAT precomputes (wave-parallel) ----
    uv1_k<<<192, 256, 0, stream>>>(Wgin, alin, arin, u2, v2);
    uv2_k<<<450, 256, 0, stream>>>(Wph, Wpp, bph, bpp, Wmt, u2, v2,
                                   vv2, wu, bc, erb, eb0);
    er2_k<<<384, 256, 0, stream>>>(hrs, vv2, erb, eb0, er);
    // WcT[j][c] = (Wph @ Wm)[c][j]
    mm64_k<true, true, 1, false, false, false, 0>
        <<<dim3(4, 4), 256, 0, stream>>>(Wmt, Wphb, WcT, 256, 256, 256,
            nullptr, 1.f);

    // ---- GCN layer 1 (reassociated): AX = Adj@Xn, X1 = relu(AX@W1*nrm+b1) ---
    xt_k<<<512, 256, 0, stream>>>(g_poi, nrm, Xnt);
    agg1_k<<<512, 512, 0, stream>>>(adj8, Xnt, AX);
    mm256_k<true, true, 1, 1, true, true>
        <<<dim3(1, 400), 512, 0, stream>>>(AX, W1t, XPN, N_NODES, 256, 64,
            nrm, b1);
    // XPN = X1 (bf16)

    // ---- GCN layer 2: Yt = (X1@W2)^T * nrm[col], agg ----
    mm256_k<true, true, 2, 2, false, false>
        <<<dim3(400, 1), 512, 0, stream>>>(W2t, XPN, Yt, 256, N_NODES, 256,
            nrm, nullptr);
    agg256_k<<<512, 512, 0, stream>>>(adj8, Yt, XPN, nrm, b2, 0);
    // XPN = poi_nodes (bf16)

    pool_k<<<B_PAR, 256, 0, stream>>>(XPN, pool, poolb);

    // ---- med similarity (output 1) ----
    med_build_k<<<B_PAR, 256, 0, stream>>>(hrs, pool, medb);
    mm64_k<true, true, 0, false, false, true, 0>
        <<<dim3(8, 8), 256, 0, stream>>>(medb, medb, med_out, 512, 512, 512,
            nullptr, 0.5f);

    // ---- UniSimGraph GCN ----
    dinv_k<<<B_PAR, 256, 0, stream>>>(med_out, dinv);
    nadj_k<<<B_PAR, 256, 0, stream>>>(med_out, dinv, nadjb);
    mm64_k<true, true, 1, false, false, false, 0>
        <<<dim3(8, 4), 256, 0, stream>>>(Whgt, hrsb, Tcatt, 256, 512, 256,
            nullptr, 1.f);
    mm64_k<true, true, 1, false, false, false, 0>
        <<<dim3(8, 4), 256, 0, stream>>>(Wpgt, poolb, Tcatt + (size_t)256 * 512,
            256, 512, 256, nullptr, 1.f);
    mm64_k<true, true, 0, false, true, false, 0>
        <<<dim3(8, 8), 256, 0, stream>>>(nadjb, Tcatt, hpagg, 512, 512, 512,
            nullptr, 1.f);

    // ---- GAT poi2img (pp never materialized) ----
    gat_poi2img_k<<<B_PAR, 256, 0, stream>>>(XPN, wu, er, q);
    // p2i = (1/3) qPN @ WpG + bgg
    mm64_k<false, true, 0, true, false, false, 0>
        <<<dim3(4, 8), 256, 0, stream>>>(q, WpG, p2i, 512, 256, 768,
            bgg, 1.f / 3.f);

    // ---- img2poi pooled: i2p = hrs @ Wc + bc ----
    mm64_k<true, true, 0, true, false, false, 0>
        <<<dim3(4, 8), 256, 0, stream>>>(hrsb, WcT, i2p, 512, 256, 256,
            bc, 1.f);

    // ---- final fc ----
    final_k<<<24, 256, 0, stream>>>(i2p, hpagg, p2i, Wfc, bfc, out);
}

// Round 9
// 391.628 us; speedup vs baseline: 1.2753x; 1.0935x over previous
//
#include <hip/hip_runtime.h>
#include <hip/hip_bf16.h>
#include <math.h>

// ---------------------------------------------------------------------------
// NGLU: B=512 parcels x P=200 poi nodes. N=102400, E=1638400, HID=256.
// Round 9: both GCN layers reassociated ((Adj@Xn)@W) and fused into two
// per-parcel kernels. gcnA: Adj-in-VGPRs + Xn-LDS -> AX1-LDS -> X1nT global
// (written transposed via D[f][d] = W1^T (x) AX1^T, no LDS transpose).
// gcnB: f-chunked Adj@X1n -> LDS -> acc += chunk@W2chunk, reg-staged
// double-ahead chunks, pool fused in epilogue. Kills the Yt 67MB round trip
// and the 70us latency-floor agg256 kernel.
// ---------------------------------------------------------------------------

#define N_NODES 102400
#define B_PAR   512
#define P_NODES 200
#define E_EDGES 1638400
#define HIDF    256

typedef __attribute__((ext_vector_type(8))) short bf16x8;
typedef __attribute__((ext_vector_type(4))) float f32x4;

__device__ __forceinline__ unsigned short f2bf(float x) {
    unsigned u = __builtin_bit_cast(unsigned, x);
    u += 0x7fffu + ((u >> 16) & 1u);               // RNE (finite data only)
    return (unsigned short)(u >> 16);
}
__device__ __forceinline__ float bf2f(unsigned short h) {
    return __builtin_bit_cast(float, (unsigned)h << 16);
}
// LDS tile [rows][64 k] bf16 = 128B/row; 16B-chunk XOR swizzle (mm64 only).
__device__ __forceinline__ int lds_off(int row, int kbyte) {
    return row * 128 + ((((kbyte >> 4) ^ (row & 7)) << 4) | (kbyte & 15));
}
template<bool BF16SRC>
__device__ __forceinline__ bf16x8 load_row8(const void* p, size_t elemoff) {
    if constexpr (BF16SRC) {
        return *(const bf16x8*)((const unsigned short*)p + elemoff);
    } else {
        const float* ap = (const float*)p + elemoff;
        float4 lo = *(const float4*)ap;
        float4 hi = *(const float4*)(ap + 4);
        union { bf16x8 v; unsigned short u[8]; } pk;
        pk.u[0] = f2bf(lo.x); pk.u[1] = f2bf(lo.y);
        pk.u[2] = f2bf(lo.z); pk.u[3] = f2bf(lo.w);
        pk.u[4] = f2bf(hi.x); pk.u[5] = f2bf(hi.y);
        pk.u[6] = f2bf(hi.z); pk.u[7] = f2bf(hi.w);
        return pk.v;
    }
}
__device__ __forceinline__ bf16x8 u8x8_to_bf16(uint2 w) {
    union { bf16x8 v; unsigned short u[8]; } r;
#pragma unroll
    for (int b = 0; b < 4; ++b) {
        r.u[b]     = (unsigned short)(__builtin_bit_cast(unsigned,
                        (float)((w.x >> (8 * b)) & 255u)) >> 16);   // exact: ints<256
        r.u[4 + b] = (unsigned short)(__builtin_bit_cast(unsigned,
                        (float)((w.y >> (8 * b)) & 255u)) >> 16);
    }
    return r.v;
}

// ------------------- fused GCN layer 1 (one block per parcel) ---------------
// X1nT[p][f][d<224] = relu((Adj@Xn @ W1)[d]*nrm_d + b1[f]) * nrm_d, transposed.
// Adj rows in VGPRs (u8), Xn^T in LDS, AX1 in LDS, D[f][d] = W1t (x) AX1.
__global__ __launch_bounds__(512, 2) void gcnA_k(
    const unsigned char* __restrict__ Adj, const float* __restrict__ gp,
    const float* __restrict__ nrm, const unsigned short* __restrict__ W1t,
    const float* __restrict__ b1, unsigned short* __restrict__ X1nT)
{
    __shared__ unsigned short lds[256 * 72];       // 36.9 KB, dual-purpose
    unsigned short* XnT = lds;                     // [64][232]  (phase 0-2)
    unsigned short* AX1 = lds;                     // [256][72]  (phase 2-3)

    const int tid  = threadIdx.x;
    const int p    = blockIdx.x;
    const int lane = tid & 63;
    const int wave = tid >> 6;
    const int frow = lane & 15;
    const int fq   = lane >> 4;                    // 0..3
    const int r4   = fq << 2;
    const f32x4 fz = {0.f, 0.f, 0.f, 0.f};

    // Adj rows (2/lane) held as u8: K=224 -> 7 slices x 8B
    uint2 adjr[2][7];
#pragma unroll
    for (int mi = 0; mi < 2; ++mi) {
        const unsigned char* ar = Adj + ((size_t)p << 16)
            + (size_t)(wave * 32 + mi * 16 + frow) * 256 + fq * 8;
#pragma unroll
        for (int ks = 0; ks < 7; ++ks)
            adjr[mi][ks] = *(const uint2*)(ar + ks * 32);
    }
    // W1t A-frags for step 3 (rows f = wave*32+mi*16+frow, k = ks*32+fq*8)
    bf16x8 w1f[2][2];
#pragma unroll
    for (int mi = 0; mi < 2; ++mi)
#pragma unroll
        for (int ks = 0; ks < 2; ++ks)
            w1f[mi][ks] = *(const bf16x8*)(W1t
                + (size_t)(wave * 32 + mi * 16 + frow) * 64 + ks * 32 + fq * 8);

    // Xn^T build: XnT[k][s] = gp[p*200+s][k] * nrm, zeros for s in [200,224)
    for (int idx = tid; idx < 224 * 16; idx += 512) {
        int s = idx >> 4, kc = idx & 15;
        float4 v = {0.f, 0.f, 0.f, 0.f};
        float nr = 0.f;
        if (s < 200) {
            v = *(const float4*)(gp + ((size_t)(p * 200 + s)) * 64 + kc * 4);
            nr = nrm[p * 200 + s];
        }
        XnT[(kc * 4 + 0) * 232 + s] = f2bf(v.x * nr);
        XnT[(kc * 4 + 1) * 232 + s] = f2bf(v.y * nr);
        XnT[(kc * 4 + 2) * 232 + s] = f2bf(v.z * nr);
        XnT[(kc * 4 + 3) * 232 + s] = f2bf(v.w * nr);
    }
    __syncthreads();

    // step 2: AX1[d][64] = Adj (x) Xn^T, per wave rows d = wave*32..+32
    f32x4 acc2[2][4];
#pragma unroll
    for (int i = 0; i < 2; ++i)
#pragma unroll
        for (int j = 0; j < 4; ++j) acc2[i][j] = fz;
#pragma unroll
    for (int ks = 0; ks < 7; ++ks) {
        bf16x8 a0 = u8x8_to_bf16(adjr[0][ks]);
        bf16x8 a1 = u8x8_to_bf16(adjr[1][ks]);
#pragma unroll
        for (int ni = 0; ni < 4; ++ni) {
            bf16x8 bfr = *(const bf16x8*)(XnT
                + (size_t)(ni * 16 + frow) * 232 + ks * 32 + fq * 8);
            acc2[0][ni] = __builtin_amdgcn_mfma_f32_16x16x32_bf16(a0, bfr, acc2[0][ni], 0, 0, 0);
            acc2[1][ni] = __builtin_amdgcn_mfma_f32_16x16x32_bf16(a1, bfr, acc2[1][ni], 0, 0, 0);
        }
    }
    __syncthreads();                               // XnT dead; alias as AX1
#pragma unroll
    for (int mi = 0; mi < 2; ++mi)
#pragma unroll
        for (int ni = 0; ni < 4; ++ni)
#pragma unroll
            for (int j = 0; j < 4; ++j)
                AX1[(size_t)(wave * 32 + mi * 16 + r4 + j) * 72 + ni * 16 + frow]
                    = f2bf(acc2[mi][ni][j]);
    __syncthreads();

    // step 3: D[f][d] = W1t (x) AX1  (per wave f-rows wave*32..+32, d all 256)
    f32x4 acc3[2][16];
#pragma unroll
    for (int i = 0; i < 2; ++i)
#pragma unroll
        for (int j = 0; j < 16; ++j) acc3[i][j] = fz;
#pragma unroll
    for (int ks = 0; ks < 2; ++ks)
#pragma unroll
        for (int ni = 0; ni < 16; ++ni) {
            bf16x8 bfr = *(const bf16x8*)(AX1
                + (size_t)(ni * 16 + frow) * 72 + ks * 32 + fq * 8);
            acc3[0][ni] = __builtin_amdgcn_mfma_f32_16x16x32_bf16(w1f[0][ks], bfr, acc3[0][ni], 0, 0, 0);
            acc3[1][ni] = __builtin_amdgcn_mfma_f32_16x16x32_bf16(w1f[1][ks], bfr, acc3[1][ni], 0, 0, 0);
        }

    // epilogue: X1nT[p][f][d] = relu(acc*nrm_d + b1[f]) * nrm_d  (d<224, 0-pad)
    float nrd[16];
#pragma unroll
    for (int ni = 0; ni < 16; ++ni) {
        int d = ni * 16 + frow;
        nrd[ni] = (d < 200) ? nrm[p * 200 + d] : 0.f;
    }
#pragma unroll
    for (int mi = 0; mi < 2; ++mi)
#pragma unroll
        for (int j = 0; j < 4; ++j) {
            int f = wave * 32 + mi * 16 + r4 + j;
            float bv = b1[f];
#pragma unroll
            for (int ni = 0; ni < 16; ++ni) {
                int d = ni * 16 + frow;
                if (d < 224) {
                    float v = fmaxf(acc3[mi][ni][j] * nrd[ni] + bv, 0.f) * nrd[ni];
                    X1nT[((size_t)p * 256 + f) * 224 + d] = f2bf(v);
                }
            }
        }
}

// ------------------- fused GCN layer 2 (one block per parcel) ---------------
// PN[g][f'] = (Adj@X1n @ W2)[d][f']*nrm_g + b2[f'], chunked over f (8 x 32);
// pool[p] = mean_d PN fused in epilogue. Adj pre-converted to bf16 VGPRs.
__global__ __launch_bounds__(512, 2) void gcnB_k(
    const unsigned char* __restrict__ Adj, const unsigned short* __restrict__ X1nT,
    const unsigned short* __restrict__ W2t, const float* __restrict__ nrm,
    const float* __restrict__ b2, unsigned short* __restrict__ PN,
    float* __restrict__ pool, unsigned short* __restrict__ poolb)
{
    __shared__ unsigned short Bb[32 * 232];        // X1nT f-chunk  (14.8 KB)
    __shared__ unsigned short AXb[256 * 40];       // AX2 chunk     (20.5 KB)
    __shared__ unsigned short W2b[256 * 40];       // W2t chunk     (20.5 KB)
    __shared__ float poolsh[256];

    const int tid  = threadIdx.x;
    const int p    = blockIdx.x;
    const int lane = tid & 63;
    const int wave = tid >> 6;
    const int frow = lane & 15;
    const int fq   = lane >> 4;
    const int r4   = fq << 2;
    const f32x4 fz = {0.f, 0.f, 0.f, 0.f};

    if (tid < 256) poolsh[tid] = 0.f;

    // Adj rows (2/lane), pre-converted to bf16 (each frag reused 8 chunks x 2)
    bf16x8 adjb[2][7];
#pragma unroll
    for (int mi = 0; mi < 2; ++mi) {
        const unsigned char* ar = Adj + ((size_t)p << 16)
            + (size_t)(wave * 32 + mi * 16 + frow) * 256 + fq * 8;
#pragma unroll
        for (int ks = 0; ks < 7; ++ks)
            adjb[mi][ks] = u8x8_to_bf16(*(const uint2*)(ar + ks * 32));
    }

    f32x4 acc5[2][16];
#pragma unroll
    for (int i = 0; i < 2; ++i)
#pragma unroll
        for (int j = 0; j < 16; ++j) acc5[i][j] = fz;

    // prologue: stage chunk 0 directly
#pragma unroll
    for (int i = 0; i < 2; ++i) {
        int idx = tid + i * 512;
        if (idx < 896) {
            int r = idx / 28, ch = idx - r * 28;
            *(uint4*)(Bb + r * 232 + ch * 8) =
                *(const uint4*)(X1nT + ((size_t)p * 256 + r) * 224 + ch * 8);
        }
        int r2 = idx >> 2, ch2 = idx & 3;
        *(uint4*)(W2b + r2 * 40 + ch2 * 8) =
            *(const uint4*)(W2t + (size_t)r2 * 256 + ch2 * 8);
    }
    __syncthreads();

    for (int c = 0; c < 8; ++c) {
        // issue next-chunk X1nT loads (latency hides under step-4 MFMAs)
        uint4 stb[2];
#pragma unroll
        for (int i = 0; i < 2; ++i) {
            int idx = tid + i * 512;
            if (c < 7 && idx < 896) {
                int r = idx / 28, ch = idx - r * 28;
                stb[i] = *(const uint4*)(X1nT
                    + ((size_t)p * 256 + (c + 1) * 32 + r) * 224 + ch * 8);
            }
        }
        // step 4: AX2chunk[d][32] = Adj (x) X1nT-chunk
        f32x4 acc4[2][2];
#pragma unroll
        for (int i = 0; i < 2; ++i)
#pragma unroll
            for (int j = 0; j < 2; ++j) acc4[i][j] = fz;
#pragma unroll
        for (int ks = 0; ks < 7; ++ks)
#pragma unroll
            for (int ni = 0; ni < 2; ++ni) {
                bf16x8 bfr = *(const bf16x8*)(Bb
                    + (size_t)(ni * 16 + frow) * 232 + ks * 32 + fq * 8);
                acc4[0][ni] = __builtin_amdgcn_mfma_f32_16x16x32_bf16(adjb[0][ks], bfr, acc4[0][ni], 0, 0, 0);
                acc4[1][ni] = __builtin_amdgcn_mfma_f32_16x16x32_bf16(adjb[1][ks], bfr, acc4[1][ni], 0, 0, 0);
            }
        __syncthreads();
        // write AX2 chunk; restage Bb for next chunk
#pragma unroll
        for (int mi = 0; mi < 2; ++mi)
#pragma unroll
            for (int ni = 0; ni < 2; ++ni)
#pragma unroll
                for (int j = 0; j < 4; ++j)
                    AXb[(size_t)(wave * 32 + mi * 16 + r4 + j) * 40 + ni * 16 + frow]
                        = f2bf(acc4[mi][ni][j]);
#pragma unroll
        for (int i = 0; i < 2; ++i) {
            int idx = tid + i * 512;
            if (c < 7 && idx < 896) {
                int r = idx / 28, ch = idx - r * 28;
                *(uint4*)(Bb + r * 232 + ch * 8) = stb[i];
            }
        }
        __syncthreads();
        // issue next-chunk W2t loads (hide under step-5 MFMAs)
        uint4 stw[2];
#pragma unroll
        for (int i = 0; i < 2; ++i) {
            int idx = tid + i * 512;
            int r = idx >> 2, ch = idx & 3;
            if (c < 7)
                stw[i] = *(const uint4*)(W2t
                    + (size_t)r * 256 + (c + 1) * 32 + ch * 8);
        }
        // step 5: acc5 += AX2chunk (x) W2chunk   (K=32, 1 slice)
        bf16x8 af[2];
        af[0] = *(const bf16x8*)(AXb + (size_t)(wave * 32 + frow) * 40 + fq * 8);
        af[1] = *(const bf16x8*)(AXb + (size_t)(wave * 32 + 16 + frow) * 40 + fq * 8);
#pragma unroll
        for (int ni = 0; ni < 16; ++ni) {
            bf16x8 bfr = *(const bf16x8*)(W2b + (size_t)(ni * 16 + frow) * 40 + fq * 8);
            acc5[0][ni] = __builtin_amdgcn_mfma_f32_16x16x32_bf16(af[0], bfr, acc5[0][ni], 0, 0, 0);
            acc5[1][ni] = __builtin_amdgcn_mfma_f32_16x16x32_bf16(af[1], bfr, acc5[1][ni], 0, 0, 0);
        }
        __syncthreads();
#pragma unroll
        for (int i = 0; i < 2; ++i) {
            int idx = tid + i * 512;
            int r = idx >> 2, ch = idx & 3;
            if (c < 7) *(uint4*)(W2b + r * 40 + ch * 8) = stw[i];
        }
        // next barrier (after step 4 of c+1) orders W2b writes before reads
    }

    // epilogue: PN write + fused pool
    float b2v[16], psum[16];
#pragma unroll
    for (int ni = 0; ni < 16; ++ni) {
        b2v[ni] = b2[ni * 16 + frow];
        psum[ni] = 0.f;
    }
#pragma unroll
    for (int mi = 0; mi < 2; ++mi)
#pragma unroll
        for (int j = 0; j < 4; ++j) {
            int d = wave * 32 + mi * 16 + r4 + j;
            if (d < 200) {
                int g = p * 200 + d;
                float nr = nrm[g];
#pragma unroll
                for (int ni = 0; ni < 16; ++ni) {
                    float v = acc5[mi][ni][j] * nr + b2v[ni];
                    PN[(size_t)g * 256 + ni * 16 + frow] = f2bf(v);
                    psum[ni] += v;
                }
            }
        }
#pragma unroll
    for (int ni = 0; ni < 16; ++ni) {
        float s = psum[ni];
        s += __shfl_xor(s, 16);
        s += __shfl_xor(s, 32);
        if (fq == 0) atomicAdd(&poolsh[ni * 16 + frow], s);
    }
    __syncthreads();
    if (tid < 256) {
        float pv = poolsh[tid] * (1.f / 200.f);
        pool[(size_t)p * 256 + tid] = pv;
        poolb[(size_t)p * 256 + tid] = f2bf(pv);
    }
}

// ----------------------- 64x64 MFMA GEMM (small shapes) ---------------------
template<bool ABF16, bool BBF16, int OMODE, bool BIASF, bool RELUF,
         bool MEDOUT, int KCHUNK>
__global__ __launch_bounds__(256) void mm64_k(
    const void* __restrict__ Ain, const void* __restrict__ Bin,
    void* __restrict__ Cout, int M, int Nc, int K,
    const float* __restrict__ bias, float alpha)
{
    __shared__ bf16x8 smem_v[1024];                 // 16 KiB
    unsigned char* Asm = (unsigned char*)smem_v;
    unsigned char* Bsm = Asm + 8192;

    const int tid  = threadIdx.x;
    const int m0   = blockIdx.y * 64;
    const int n0   = blockIdx.x * 64;
    const int sr   = tid >> 3, sc = tid & 7;
    const int lane = tid & 63;
    const int wm   = (tid >> 7) & 1, wn = (tid >> 6) & 1;
    const int frow = lane & 15;
    const int fko  = (lane >> 4) << 4;

    int kbeg = 0, kend = K;
    float* Cf = (float*)Cout;
    if (KCHUNK > 0) {
        kbeg = blockIdx.z * KCHUNK; kend = kbeg + KCHUNK;
        Cf += (size_t)blockIdx.z * M * Nc;
    }

    f32x4 acc[2][2];
    const f32x4 fz = {0.f, 0.f, 0.f, 0.f};
#pragma unroll
    for (int i = 0; i < 2; ++i)
#pragma unroll
        for (int j = 0; j < 2; ++j) acc[i][j] = fz;

    bf16x8 areg[2], breg[2];
    auto load_tiles = [&](int k0) {
#pragma unroll
        for (int i = 0; i < 2; ++i) {
            int row = sr + 32 * i;
            areg[i] = load_row8<ABF16>(Ain, (size_t)(m0 + row) * K + k0 + sc * 8);
            breg[i] = load_row8<BBF16>(Bin, (size_t)(n0 + row) * K + k0 + sc * 8);
        }
    };

    load_tiles(kbeg);
    for (int k0 = kbeg; k0 < kend; k0 += 64) {
        __syncthreads();
#pragma unroll
        for (int i = 0; i < 2; ++i) {
            *(bf16x8*)(Asm + lds_off(sr + 32 * i, sc * 16)) = areg[i];
            *(bf16x8*)(Bsm + lds_off(sr + 32 * i, sc * 16)) = breg[i];
        }
        __syncthreads();
        if (k0 + 64 < kend) load_tiles(k0 + 64);
#pragma unroll
        for (int ks = 0; ks < 2; ++ks) {
            const int kb = ks * 64 + fko;
            bf16x8 af[2], bfr[2];
#pragma unroll
            for (int t = 0; t < 2; ++t)
                af[t] = *(const bf16x8*)(Asm + lds_off(wm * 32 + t * 16 + frow, kb));
#pragma unroll
            for (int t = 0; t < 2; ++t)
                bfr[t] = *(const bf16x8*)(Bsm + lds_off(wn * 32 + t * 16 + frow, kb));
#pragma unroll
            for (int mi = 0; mi < 2; ++mi)
#pragma unroll
                for (int ni = 0; ni < 2; ++ni)
                    acc[mi][ni] = __builtin_amdgcn_mfma_f32_16x16x32_bf16(
                        af[mi], bfr[ni], acc[mi][ni], 0, 0, 0);
        }
    }

    const int r4 = (lane >> 4) << 2;
#pragma unroll
    for (int mi = 0; mi < 2; ++mi) {
#pragma unroll
        for (int ni = 0; ni < 2; ++ni) {
            int col = n0 + wn * 32 + ni * 16 + frow;
#pragma unroll
            for (int j = 0; j < 4; ++j) {
                int row = m0 + wm * 32 + mi * 16 + r4 + j;
                float v = acc[mi][ni][j] * alpha;
                if (BIASF)  v += bias[col];
                if (RELUF)  v = fmaxf(v, 0.f);
                if (MEDOUT) v += 0.5f;
                if (OMODE == 0) {
                    Cf[(size_t)row * Nc + col] = v;
                } else {
                    ((unsigned short*)Cout)[(size_t)row * Nc + col] = f2bf(v);
                }
            }
        }
    }
}

// ------------------------- graph preprocessing -----------------------------
__global__ __launch_bounds__(256) void edge_diag_k(
    const int* __restrict__ esrc, const int* __restrict__ edst,
    unsigned char* __restrict__ A)
{
    int id = blockIdx.x * 256 + threadIdx.x;        // E + N = 1740800
    size_t bo;
    if (id < E_EDGES) {
        int s = esrc[id], d = edst[id];
        int p = d / 200;
        int dl = d - p * 200, sl = s - p * 200;
        bo = (((size_t)(p * 256 + dl)) << 8) + (unsigned)sl;
    } else {
        int i2 = id - E_EDGES;                      // < N
        int p = i2 / 200, d = i2 - p * 200;
        bo = (((size_t)(p * 256 + d)) << 8) + (unsigned)d;
    }
    atomicAdd((unsigned int*)(A + (bo & ~(size_t)3)), 1u << ((bo & 3) * 8));
}

__global__ __launch_bounds__(256) void norm2_k(const unsigned char* __restrict__ A,
                                               float* __restrict__ nrm)
{
    int g = blockIdx.x * 256 + threadIdx.x;
    int p = g / 200, d = g - p * 200;
    const uint4* row = (const uint4*)(A + (((size_t)(p * 256 + d)) << 8));
    unsigned s = 0;
#pragma unroll
    for (int i = 0; i < 16; ++i) {
        uint4 w = row[i];
        unsigned a = w.x, b = w.y, c = w.z, e = w.w;
        s += (a & 255) + ((a >> 8) & 255) + ((a >> 16) & 255) + (a >> 24);
        s += (b & 255) + ((b >> 8) & 255) + ((b >> 16) & 255) + (b >> 24);
        s += (c & 255) + ((c >> 8) & 255) + ((c >> 16) & 255) + (c >> 24);
        s += (e & 255) + ((e >> 8) & 255) + ((e >> 16) & 255) + (e >> 24);
    }
    nrm[g] = rsqrtf((float)s);                      // row-sum = in-deg + self
}

// ------------- all weight transposes/casts + img cast -----------------------
__global__ __launch_bounds__(256) void prep_k(
    const float* __restrict__ W1, const float* __restrict__ W2,
    const float* __restrict__ Whg,
    const float* __restrict__ Wpg, const float* __restrict__ Whrs,
    const float* __restrict__ Wgin, const float* __restrict__ Wgw,
    const float* __restrict__ Wph, const float* __restrict__ img,
    unsigned short* __restrict__ W1t, unsigned short* __restrict__ W2t,
    unsigned short* __restrict__ Whgt,
    unsigned short* __restrict__ Wpgt, unsigned short* __restrict__ Whrst,
    unsigned short* __restrict__ Wgint, unsigned short* __restrict__ Wmt,
    unsigned short* __restrict__ Wphb, unsigned short* __restrict__ imgb)
{
    int b = blockIdx.x, tid = threadIdx.x;
    if (b < 64) {                 // W1t [256][64]
        int id = b * 256 + tid; int n = id >> 6, k = id & 63;
        W1t[id] = f2bf(W1[(size_t)k * 256 + n]);
    } else if (b < 320) {         // W2t [256][256]
        int id = (b - 64) * 256 + tid; int n = id >> 8, k = id & 255;
        W2t[id] = f2bf(W2[(size_t)k * 256 + n]);
    } else if (b < 576) {         // Whgt
        int id = (b - 320) * 256 + tid; int n = id >> 8, k = id & 255;
        Whgt[id] = f2bf(Whg[(size_t)k * 256 + n]);
    } else if (b < 832) {         // Wpgt
        int id = (b - 576) * 256 + tid; int n = id >> 8, k = id & 255;
        Wpgt[id] = f2bf(Wpg[(size_t)k * 256 + n]);
    } else if (b < 2880) {        // Whrst [256][2048]
        int id = (b - 832) * 256 + tid; int n = id >> 11, k = id & 2047;
        Whrst[id] = f2bf(Whrs[(size_t)k * 256 + n]);
    } else if (b < 3648) {        // Wgint [256][768], k-order = h*256+t
        int id = (b - 2880) * 256 + tid; int j = id / 768, k2 = id - j * 768;
        int t = k2 & 255, h = k2 >> 8;
        Wgint[id] = f2bf(Wgin[(size_t)t * 768 + h * 256 + j]);
    } else if (b < 3904) {        // Wmt [256 j][256 t] = mean_h Wgw / (1+1e-9)
        int id = (b - 3648) * 256 + tid; int j = id >> 8, t = id & 255;
        const float c3 = (1.f / 3.f) * (1.f / (1.f + 1e-9f));
        float s = Wgw[(size_t)t * 768 + j] + Wgw[(size_t)t * 768 + 256 + j] +
                  Wgw[(size_t)t * 768 + 512 + j];
        Wmt[id] = f2bf(s * c3);
    } else if (b < 4160) {        // Wphb cast
        int id = (b - 3904) * 256 + tid;
        Wphb[id] = f2bf(Wph[id]);
    } else {                      // imgb cast [512][2048]
        int id = (b - 4160) * 256 + tid;
        imgb[id] = f2bf(img[id]);
    }
}

// --- WpG[j][(h,c)] = sum_t Wpp[c][t]*Wgin[t][h*256+j]; bgg[j] (bias fold) ----
__global__ __launch_bounds__(256) void wpg_k(
    const float* __restrict__ Wpp, const float* __restrict__ Wgin,
    const float* __restrict__ bpp,
    unsigned short* __restrict__ WpG, float* __restrict__ bgg)
{
    __shared__ float wsh[256];
    const int b = blockIdx.x, j = threadIdx.x;
    if (b < 768) {
        int h = b >> 8, c = b & 255;
        wsh[j] = Wpp[(size_t)c * 256 + j];
        __syncthreads();
        float acc = 0.f;
        for (int t = 0; t < 256; ++t)
            acc += wsh[t] * Wgin[(size_t)t * 768 + h * 256 + j];
        WpG[(size_t)j * 768 + h * 256 + c] = f2bf(acc);
    } else {
        float s = 0.f;
        for (int h = 0; h < 3; ++h)
            for (int t = 0; t < 256; ++t)
                s += bpp[t] * Wgin[(size_t)t * 768 + h * 256 + j];
        bgg[j] = s * (1.f / 3.f);
    }
}

// --------------------------- hrs split-K reduce -----------------------------
__global__ __launch_bounds__(256) void hrs_reduce_k(
    const float* __restrict__ part, const float* __restrict__ bhrs,
    float* __restrict__ hrs, unsigned short* __restrict__ hrsb)
{
    int id = blockIdx.x * 256 + threadIdx.x;        // 131072
    float s = bhrs[id & 255];
#pragma unroll
    for (int z = 0; z < 8; ++z) s += part[(size_t)z * 131072 + id];
    hrs[id] = s;
    hrsb[id] = f2bf(s);
}

// ------------------- med = rownorm(concat(hrs, pool)) -----------------------
__global__ __launch_bounds__(256) void med_build_k(
    const float* __restrict__ hrs, const float* __restrict__ pool,
    unsigned short* __restrict__ medb)
{
    __shared__ float red[256];
    int b = blockIdx.x, f = threadIdx.x;
    float v0 = hrs[(size_t)b * 256 + f];
    float v1 = pool[(size_t)b * 256 + f];
    red[f] = v0 * v0 + v1 * v1;
    __syncthreads();
    for (int s = 128; s > 0; s >>= 1) {
        if (f < s) red[f] += red[f + s];
        __syncthreads();
    }
    float inv = rsqrtf(red[0]);
    medb[(size_t)b * 512 + f]       = f2bf(v0 * inv);
    medb[(size_t)b * 512 + 256 + f] = f2bf(v1 * inv);
}

// ---------------------- thresholded-similarity GCN --------------------------
__global__ __launch_bounds__(256) void dinv_k(const float* __restrict__ mo,
                                              float* __restrict__ dinv)
{
    __shared__ int red[256];
    int i = blockIdx.x, t = threadIdx.x;
    int c = 0;
    for (int j = t; j < 512; j += 256) c += (mo[(size_t)i * 512 + j] >= 0.9f) ? 1 : 0;
    red[t] = c; __syncthreads();
    for (int s = 128; s > 0; s >>= 1) {
        if (t < s) red[t] += red[t + s];
        __syncthreads();
    }
    if (t == 0) dinv[i] = rsqrtf((float)red[0]);
}

__global__ __launch_bounds__(256) void nadj_k(const float* __restrict__ mo,
                                              const float* __restrict__ dinv,
                                              unsigned short* __restrict__ nadjb)
{
    int i = blockIdx.x, t = threadIdx.x;
    float di = dinv[i];
    for (int j = t; j < 512; j += 256) {
        float a = (mo[(size_t)i * 512 + j] >= 0.9f || j == i) ? 1.f : 0.f;
        nadjb[(size_t)i * 512 + j] = f2bf(a * di * dinv[j]);
    }
}

// ---------------- GAT precomputes: wave-parallel dot products ---------------
__global__ __launch_bounds__(256) void uv1_k(
    const float* __restrict__ Wgin, const float* __restrict__ al,
    const float* __restrict__ ar,
    float* __restrict__ u2, float* __restrict__ v2)
{
    const int wave = threadIdx.x >> 6, lane = threadIdx.x & 63;
    const int task = blockIdx.x * 4 + wave;         // < 768
    const int k = task / 3, h = task - k * 3;
    float4 w = *(const float4*)(Wgin + (size_t)k * 768 + h * 256 + lane * 4);
    float4 a = *(const float4*)(al + h * 256 + lane * 4);
    float4 r = *(const float4*)(ar + h * 256 + lane * 4);
    float su = w.x * a.x + w.y * a.y + w.z * a.z + w.w * a.w;
    float sv = w.x * r.x + w.y * r.y + w.z * r.z + w.w * r.w;
#pragma unroll
    for (int o = 32; o > 0; o >>= 1) {
        su += __shfl_xor(su, o);
        sv += __shfl_xor(sv, o);
    }
    if (lane == 0) { u2[task] = su; v2[task] = sv; }
}

__global__ __launch_bounds__(256) void uv2_k(
    const float* __restrict__ Wph, const float* __restrict__ Wpp,
    const float* __restrict__ bph, const float* __restrict__ bpp,
    const unsigned short* __restrict__ Wmt,
    const float* __restrict__ u2, const float* __restrict__ v2,
    float* __restrict__ vv2, float* __restrict__ wu,
    float* __restrict__ bc, float* __restrict__ erb, float* __restrict__ eb0)
{
    __shared__ float ush[768], vsh[768];
    const int tid = threadIdx.x;
    for (int i = tid; i < 768; i += 256) { ush[i] = u2[i]; vsh[i] = v2[i]; }
    __syncthreads();
    const int wave = tid >> 6, lane = tid & 63;
    const int task = blockIdx.x * 4 + wave;
    float s = 0.f;
    if (task < 1536) {
        int t2 = task < 768 ? task : task - 768;
        int k = t2 / 3, h = t2 - k * 3;
        const float* W = task < 768 ? Wph : Wpp;
        const float* vec = task < 768 ? vsh : ush;
        float4 w = *(const float4*)(W + (size_t)k * 256 + lane * 4);
        s = w.x * vec[(lane * 4 + 0) * 3 + h] + w.y * vec[(lane * 4 + 1) * 3 + h]
          + w.z * vec[(lane * 4 + 2) * 3 + h] + w.w * vec[(lane * 4 + 3) * 3 + h];
#pragma unroll
        for (int o = 32; o > 0; o >>= 1) s += __shfl_xor(s, o);
        if (lane == 0) { if (task < 768) vv2[t2] = s; else wu[t2] = s; }
    } else if (task < 1792) {
        int k = task - 1536;
        float4 b4 = *(const float4*)(bph + lane * 4);
        const unsigned short* wm = Wmt + (size_t)k * 256 + lane * 4;
        s = b4.x * bf2f(wm[0]) + b4.y * bf2f(wm[1])
          + b4.z * bf2f(wm[2]) + b4.w * bf2f(wm[3]);
#pragma unroll
        for (int o = 32; o > 0; o >>= 1) s += __shfl_xor(s, o);
        if (lane == 0) bc[k] = s;
    } else if (task < 1798) {
        int t2 = task - 1792;
        int h = t2 % 3;
        bool second = t2 >= 3;
        const float* bias = second ? bpp : bph;
        const float* vec  = second ? ush : vsh;
        float4 b4 = *(const float4*)(bias + lane * 4);
        s = b4.x * vec[(lane * 4 + 0) * 3 + h] + b4.y * vec[(lane * 4 + 1) * 3 + h]
          + b4.z * vec[(lane * 4 + 2) * 3 + h] + b4.w * vec[(lane * 4 + 3) * 3 + h];
#pragma unroll
        for (int o = 32; o > 0; o >>= 1) s += __shfl_xor(s, o);
        if (lane == 0) { if (second) eb0[h] = s; else erb[h] = s; }
    }
}

__global__ __launch_bounds__(256) void er2_k(
    const float* __restrict__ hrs, const float* __restrict__ vv2,
    const float* __restrict__ erb, const float* __restrict__ eb0,
    float* __restrict__ er)
{
    __shared__ float vsh[768];
    const int tid = threadIdx.x;
    for (int i = tid; i < 768; i += 256) vsh[i] = vv2[i];
    __syncthreads();
    const int wave = tid >> 6, lane = tid & 63;
    const int task = blockIdx.x * 4 + wave;         // < 1536
    const int b = task / 3, h = task - b * 3;
    float4 hv = *(const float4*)(hrs + (size_t)b * 256 + lane * 4);
    float s = hv.x * vsh[(lane * 4 + 0) * 3 + h] + hv.y * vsh[(lane * 4 + 1) * 3 + h]
            + hv.z * vsh[(lane * 4 + 2) * 3 + h] + hv.w * vsh[(lane * 4 + 3) * 3 + h];
#pragma unroll
    for (int o = 32; o > 0; o >>= 1) s += __shfl_xor(s, o);
    if (lane == 0) er[task] = erb[h] + eb0[h] + s;
}

// Per-parcel: el = PN@wu, e = leaky(el+er), softmax over 200 nodes/head,
// qPN[b,h,:] = sum_n alpha[n,h] * PN[n,:]
__global__ __launch_bounds__(256) void gat_poi2img_k(
    const unsigned short* __restrict__ PN, const float* __restrict__ wu,
    const float* __restrict__ er, float* __restrict__ q)
{
    __shared__ float esh[600];
    __shared__ float ash[600];
    __shared__ float ush[768];
    __shared__ float mz[8];
    const int p = blockIdx.x, tid = threadIdx.x;
    const size_t base = (size_t)p * P_NODES;

    for (int i = tid; i < 768; i += 256) ush[i] = wu[i];
    __syncthreads();

    for (int it = tid; it < 600; it += 256) {
        int n = it / 3, h = it % 3;
        const unsigned short* row = PN + (base + n) * HIDF;
        float s = 0.f;
        for (int k = 0; k < 256; k += 8) {
            union { uint4 qv; unsigned short us[8]; } w;
            w.qv = *(const uint4*)(row + k);
#pragma unroll
            for (int j = 0; j < 8; ++j) s += bf2f(w.us[j]) * ush[(k + j) * 3 + h];
        }
        s += er[p * 3 + h];
        esh[it] = s > 0.f ? s : 0.2f * s;
    }
    __syncthreads();

    int wave = tid >> 6, lane = tid & 63;
    if (wave < 3) {
        float mx = -1e30f;
        for (int n = lane; n < P_NODES; n += 64) mx = fmaxf(mx, esh[n * 3 + wave]);
        for (int o = 32; o > 0; o >>= 1) mx = fmaxf(mx, __shfl_xor(mx, o));
        float sm = 0.f;
        for (int n = lane; n < P_NODES; n += 64) sm += expf(esh[n * 3 + wave] - mx);
        for (int o = 32; o > 0; o >>= 1) sm += __shfl_xor(sm, o);
        if (lane == 0) { mz[wave] = mx; mz[4 + wave] = sm; }
    }
    __syncthreads();

    for (int it = tid; it < 600; it += 256) {
        int h = it % 3;
        ash[it] = expf(esh[it] - mz[h]) / (mz[4 + h] + 1e-9f);
    }
    __syncthreads();

    float a0 = 0.f, a1 = 0.f, a2 = 0.f;
    for (int n = 0; n < P_NODES; ++n) {
        float vv = bf2f(PN[(base + n) * HIDF + tid]);
        a0 += ash[n * 3 + 0] * vv;
        a1 += ash[n * 3 + 1] * vv;
        a2 += ash[n * 3 + 2] * vv;
    }
    q[((size_t)p * 3 + 0) * 256 + tid] = a0;
    q[((size_t)p * 3 + 1) * 256 + tid] = a1;
    q[((size_t)p * 3 + 2) * 256 + tid] = a2;
}

// --------------------------- final projection -------------------------------
__global__ __launch_bounds__(256) void final_k(
    const float* __restrict__ i2p, const float* __restrict__ hpagg,
    const float* __restrict__ p2i,
    const float* __restrict__ Wfc, const float* __restrict__ bfc,
    float* __restrict__ out)
{
    int id = blockIdx.x * 256 + threadIdx.x;
    if (id >= B_PAR * 12) return;
    int b = id / 12, o = id % 12;
    float acc = bfc[o];
    const float* s0 = i2p + (size_t)b * 256;          // img2poi_pooled
    const float* s1 = hpagg + (size_t)b * 512 + 256;  // poi_agg
    const float* s2 = p2i + (size_t)b * 256;          // poi2img
    const float* s3 = hpagg + (size_t)b * 512;        // hrs_agg
    for (int k = 0; k < 256; ++k) {
        acc += s0[k] * Wfc[(size_t)(0 * 256 + k) * 12 + o];
        acc += s1[k] * Wfc[(size_t)(1 * 256 + k) * 12 + o];
        acc += s2[k] * Wfc[(size_t)(2 * 256 + k) * 12 + o];
        acc += s3[k] * Wfc[(size_t)(3 * 256 + k) * 12 + o];
    }
    out[id] = acc;
}

// ---------------------------------------------------------------------------
extern "C" void kernel_launch(void* const* d_in, const int* in_sizes, int n_in,
                              void* d_out, int out_size, void* d_ws, size_t ws_size,
                              hipStream_t stream)
{
    const float* g_poi = (const float*)d_in[0];
    const float* img   = (const float*)d_in[1];
    const int*   esrc  = (const int*)d_in[2];
    const int*   edst  = (const int*)d_in[3];
    const float* W1    = (const float*)d_in[4];
    const float* b1    = (const float*)d_in[5];
    const float* W2    = (const float*)d_in[6];
    const float* b2    = (const float*)d_in[7];
    const float* Whrs  = (const float*)d_in[8];
    const float* bhrs  = (const float*)d_in[9];
    const float* Wph   = (const float*)d_in[10];
    const float* bph   = (const float*)d_in[11];
    const float* Wpp   = (const float*)d_in[12];
    const float* bpp   = (const float*)d_in[13];
    const float* Wgin  = (const float*)d_in[14];
    const float* alin  = (const float*)d_in[15];
    const float* arin  = (const float*)d_in[16];
    const float* Wgw   = (const float*)d_in[17];
    // d_in[18]/d_in[19] (al_with/ar_with) numerically dead: each poi node has
    // exactly one incoming parcel edge -> edge-softmax weight = 1/(1+1e-9).
    const float* Whg   = (const float*)d_in[20];
    const float* Wpg   = (const float*)d_in[21];
    const float* Wfc   = (const float*)d_in[22];
    const float* bfc   = (const float*)d_in[23];

    float* out     = (float*)d_out;
    float* med_out = out + B_PAR * 12;

    char* ws = (char*)d_ws;
    size_t off = 0;
    auto take = [&](size_t bytes) { void* pv = ws + off; off += (bytes + 255) & ~(size_t)255; return pv; };

    unsigned char*  adj8 = (unsigned char*)take((size_t)B_PAR * 256 * 256);     // 33.6MB
    unsigned short* X1nT = (unsigned short*)take((size_t)B_PAR * 256 * 224 * 2);// 58.7MB
    unsigned short* XPN  = (unsigned short*)take((size_t)N_NODES * 256 * 2);    // 52.4MB
    float*          part = (float*)take((size_t)8 * 512 * 256 * 4);             // 4.2MB

    unsigned short* W1t   = (unsigned short*)take(256 * 64 * 2);
    unsigned short* W2t   = (unsigned short*)take(256 * 256 * 2);
    unsigned short* Whgt  = (unsigned short*)take(256 * 256 * 2);
    unsigned short* Wpgt  = (unsigned short*)take(256 * 256 * 2);
    unsigned short* Whrst = (unsigned short*)take((size_t)256 * 2048 * 2);
    unsigned short* Wgint = (unsigned short*)take((size_t)256 * 768 * 2);
    unsigned short* Wmt   = (unsigned short*)take(256 * 256 * 2);
    unsigned short* Wphb  = (unsigned short*)take(256 * 256 * 2);
    unsigned short* WcT   = (unsigned short*)take(256 * 256 * 2);
    unsigned short* WpG   = (unsigned short*)take((size_t)256 * 768 * 2);
    unsigned short* imgb  = (unsigned short*)take((size_t)512 * 2048 * 2);
    unsigned short* hrsb  = (unsigned short*)take((size_t)B_PAR * 256 * 2);
    unsigned short* poolb = (unsigned short*)take((size_t)B_PAR * 256 * 2);
    unsigned short* medb  = (unsigned short*)take((size_t)B_PAR * 512 * 2);
    unsigned short* nadjb = (unsigned short*)take((size_t)B_PAR * 512 * 2);
    unsigned short* Tcatt = (unsigned short*)take((size_t)512 * 512 * 2);
    float* nrm   = (float*)take((size_t)N_NODES * 4);
    float* hrs   = (float*)take((size_t)B_PAR * 256 * 4);
    float* pool  = (float*)take((size_t)B_PAR * 256 * 4);
    float* dinv  = (float*)take((size_t)B_PAR * 4);
    float* hpagg = (float*)take((size_t)B_PAR * 512 * 4);
    float* u2    = (float*)take(768 * 4);
    float* v2    = (float*)take(768 * 4);
    float* wu    = (float*)take(768 * 4);
    float* vv2   = (float*)take(768 * 4);
    float* erb   = (float*)take(16);
    float* eb0   = (float*)take(16);
    float* bc    = (float*)take(256 * 4);
    float* bgg   = (float*)take(256 * 4);
    float* er    = (float*)take((size_t)B_PAR * 3 * 4);
    float* q     = (float*)take((size_t)B_PAR * 768 * 4);
    float* p2i   = (float*)take((size_t)B_PAR * 256 * 4);
    float* i2p   = (float*)take((size_t)B_PAR * 256 * 4);
    (void)ws_size; (void)in_sizes; (void)n_in; (void)out_size;

    // ---- preprocessing ----
    hipMemsetAsync(adj8, 0, (size_t)B_PAR * 256 * 256, stream);
    prep_k<<<8256, 256, 0, stream>>>(W1, W2, Whg, Wpg, Whrs, Wgin, Wgw,
        Wph, img, W1t, W2t, Whgt, Wpgt, Whrst, Wgint, Wmt, Wphb, imgb);
    edge_diag_k<<<(E_EDGES + N_NODES) / 256, 256, 0, stream>>>(esrc, edst, adj8);
    norm2_k<<<N_NODES / 256, 256, 0, stream>>>(adj8, nrm);
    wpg_k<<<769, 256, 0, stream>>>(Wpp, Wgin, bpp, WpG, bgg);

    // ---- hrs encoder: split-K (8x256) 64-tile MFMA + reduce ----
    mm64_k<true, true, 0, false, false, false, 256>
        <<<dim3(4, 8, 8), 256, 0, stream>>>(imgb, Whrst, part, 512, 256, 2048,
            nullptr, 1.f);
    hrs_reduce_k<<<512, 256, 0, stream>>>(part, bhrs, hrs, hrsb);

    // ---- GAT precomputes (wave-parallel) ----
    uv1_k<<<192, 256, 0, stream>>>(Wgin, alin, arin, u2, v2);
    uv2_k<<<450, 256, 0, stream>>>(Wph, Wpp, bph, bpp, Wmt, u2, v2,
                                   vv2, wu, bc, erb, eb0);
    er2_k<<<384, 256, 0, stream>>>(hrs, vv2, erb, eb0, er);
    // WcT[j][c] = (Wph @ Wm)[c][j]
    mm64_k<true, true, 1, false, false, false, 0>
        <<<dim3(4, 4), 256, 0, stream>>>(Wmt, Wphb, WcT, 256, 256, 256,
            nullptr, 1.f);

    // ---- fused GCN: layer 1 -> X1nT ; layer 2 -> poi_nodes + pool ----
    gcnA_k<<<B_PAR, 512, 0, stream>>>(adj8, g_poi, nrm, W1t, b1, X1nT);
    gcnB_k<<<B_PAR, 512, 0, stream>>>(adj8, X1nT, W2t, nrm, b2, XPN,
                                      pool, poolb);

    // ---- med similarity (output 1) ----
    med_build_k<<<B_PAR, 256, 0, stream>>>(hrs, pool, medb);
    mm64_k<true, true, 0, false, false, true, 0>
        <<<dim3(8, 8), 256, 0, stream>>>(medb, medb, med_out, 512, 512, 512,
            nullptr, 0.5f);

    // ---- UniSimGraph GCN ----
    dinv_k<<<B_PAR, 256, 0, stream>>>(med_out, dinv);
    nadj_k<<<B_PAR, 256, 0, stream>>>(med_out, dinv, nadjb);
    mm64_k<true, true, 1, false, false, false, 0>
        <<<dim3(8, 4), 256, 0, stream>>>(Whgt, hrsb, Tcatt, 256, 512, 256,
            nullptr, 1.f);
    mm64_k<true, true, 1, false, false, false, 0>
        <<<dim3(8, 4), 256, 0, stream>>>(Wpgt, poolb, Tcatt + (size_t)256 * 512,
            256, 512, 256, nullptr, 1.f);
    mm64_k<true, true, 0, false, true, false, 0>
        <<<dim3(8, 8), 256, 0, stream>>>(nadjb, Tcatt, hpagg, 512, 512, 512,
            nullptr, 1.f);

    // ---- GAT poi2img (pp never materialized) ----
    gat_poi2img_k<<<B_PAR, 256, 0, stream>>>(XPN, wu, er, q);
    // p2i = (1/3) qPN @ WpG + bgg
    mm64_k<false, true, 0, true, false, false, 0>
        <<<dim3(4, 8), 256, 0, stream>>>(q, WpG, p2i, 512, 256, 768,
            bgg, 1.f / 3.f);

    // ---- img2poi pooled: i2p = hrs @ Wc + bc ----
    mm64_k<true, true, 0, true, false, false, 0>
        <<<dim3(4, 8), 256, 0, stream>>>(hrsb, WcT, i2p, 512, 256, 256,
            bc, 1.f);

    // ---- final fc ----
    final_k<<<24, 256, 0, stream>>>(i2p, hpagg, p2i, Wfc, bfc, out);
}

// Round 10
// 367.001 us; speedup vs baseline: 1.3609x; 1.0671x over previous
//
#include <hip/hip_runtime.h>
#include <hip/hip_bf16.h>
#include <math.h>

// ---------------------------------------------------------------------------
// NGLU: B=512 parcels x P=200 poi nodes. N=102400, E=1638400, HID=256.
// Round 10: (1) GAT poi2img fused into gcnBG epilogue -> PN (52MB) never
// materialized; q computed from f32 PN held in registers. (2) All per-parcel
// LDS tiles moved to the conflict-free lds_off 128B-row XOR layout; the
// Adj-MFMA steps are operand-swapped (C[k][d]) so acc->LDS becomes one b64
// write per fragment instead of 16 scalar u16s (round-9: 5.4M conflicts).
// ---------------------------------------------------------------------------

#define N_NODES 102400
#define B_PAR   512
#define P_NODES 200
#define E_EDGES 1638400
#define HIDF    256

typedef __attribute__((ext_vector_type(8))) short bf16x8;
typedef __attribute__((ext_vector_type(4))) float f32x4;

__device__ __forceinline__ unsigned short f2bf(float x) {
    unsigned u = __builtin_bit_cast(unsigned, x);
    u += 0x7fffu + ((u >> 16) & 1u);               // RNE (finite data only)
    return (unsigned short)(u >> 16);
}
__device__ __forceinline__ float bf2f(unsigned short h) {
    return __builtin_bit_cast(float, (unsigned)h << 16);
}
// 128B rows, 16B-chunk XOR swizzle (proven 0-conflict in rounds 3-8).
__device__ __forceinline__ int lds_off(int row, int kbyte) {
    return row * 128 + ((((kbyte >> 4) ^ (row & 7)) << 4) | (kbyte & 15));
}
// 64B rows, 2-bit XOR (4-way worst case; used for the small W2 chunk only).
__device__ __forceinline__ int w2off(int row, int kbyte) {
    return row * 64 + (((((kbyte >> 4) & 3) ^ (row & 3)) << 4) | (kbyte & 15));
}
template<bool BF16SRC>
__device__ __forceinline__ bf16x8 load_row8(const void* p, size_t elemoff) {
    if constexpr (BF16SRC) {
        return *(const bf16x8*)((const unsigned short*)p + elemoff);
    } else {
        const float* ap = (const float*)p + elemoff;
        float4 lo = *(const float4*)ap;
        float4 hi = *(const float4*)(ap + 4);
        union { bf16x8 v; unsigned short u[8]; } pk;
        pk.u[0] = f2bf(lo.x); pk.u[1] = f2bf(lo.y);
        pk.u[2] = f2bf(lo.z); pk.u[3] = f2bf(lo.w);
        pk.u[4] = f2bf(hi.x); pk.u[5] = f2bf(hi.y);
        pk.u[6] = f2bf(hi.z); pk.u[7] = f2bf(hi.w);
        return pk.v;
    }
}
__device__ __forceinline__ bf16x8 u8x8_to_bf16(uint2 w) {
    union { bf16x8 v; unsigned short u[8]; } r;
#pragma unroll
    for (int b = 0; b < 4; ++b) {
        r.u[b]     = (unsigned short)(__builtin_bit_cast(unsigned,
                        (float)((w.x >> (8 * b)) & 255u)) >> 16);   // exact: ints<256
        r.u[4 + b] = (unsigned short)(__builtin_bit_cast(unsigned,
                        (float)((w.y >> (8 * b)) & 255u)) >> 16);
    }
    return r.v;
}
__device__ __forceinline__ unsigned long long pack4bf(f32x4 v) {
    union { unsigned long long u; unsigned short h[4]; } pk;
    pk.h[0] = f2bf(v[0]); pk.h[1] = f2bf(v[1]);
    pk.h[2] = f2bf(v[2]); pk.h[3] = f2bf(v[3]);
    return pk.u;
}

// ------------------- fused GCN layer 1 (one block per parcel) ---------------
// X1nT[p][f][d<224] = relu((Adj@Xn @ W1)[d]*nrm_d + b1[f]) * nrm_d, transposed.
// XnT rows = seg*64+k (lds_off); step2 operand-swapped -> C[k][d] -> b64
// writes into AX1[d][k] (lds_off); step3 D[f][d] = W1t (x) AX1.
__global__ __launch_bounds__(512, 2) void gcnA_k(
    const unsigned char* __restrict__ Adj, const float* __restrict__ gp,
    const float* __restrict__ nrm, const unsigned short* __restrict__ W1t,
    const float* __restrict__ b1, unsigned short* __restrict__ X1nT)
{
    __shared__ unsigned char XnU[32768];           // XnT [seg*64+k][64 s]
    __shared__ unsigned char AXU[32768];           // AX1 [d][64 k]

    const int tid  = threadIdx.x;
    const int p    = blockIdx.x;
    const int lane = tid & 63;
    const int wave = tid >> 6;
    const int frow = lane & 15;
    const int fq   = lane >> 4;
    const int r4   = fq << 2;
    const f32x4 fz = {0.f, 0.f, 0.f, 0.f};

    // Adj rows (2/lane) as u8: rows wave*32+mi*16+frow, bytes ks*32+fq*8
    uint2 adjr[2][7];
#pragma unroll
    for (int mi = 0; mi < 2; ++mi) {
        const unsigned char* ar = Adj + ((size_t)p << 16)
            + (size_t)(wave * 32 + mi * 16 + frow) * 256 + fq * 8;
#pragma unroll
        for (int ks = 0; ks < 7; ++ks)
            adjr[mi][ks] = *(const uint2*)(ar + ks * 32);
    }
    // W1t A-frags for step 3
    bf16x8 w1f[2][2];
#pragma unroll
    for (int mi = 0; mi < 2; ++mi)
#pragma unroll
        for (int ks = 0; ks < 2; ++ks)
            w1f[mi][ks] = *(const bf16x8*)(W1t
                + (size_t)(wave * 32 + mi * 16 + frow) * 64 + ks * 32 + fq * 8);

    // XnT build: lane = k; per 8-s group one coalesced pass + one b128 write
    for (int gi = wave; gi < 28; gi += 8) {
        int s0 = gi * 8;
        union { bf16x8 v; unsigned short h[8]; } pk;
#pragma unroll
        for (int t = 0; t < 8; ++t) {
            int s = s0 + t;
            float val = 0.f;
            if (s < 200)
                val = gp[((size_t)(p * 200 + s)) * 64 + lane] * nrm[p * 200 + s];
            pk.h[t] = f2bf(val);
        }
        *(bf16x8*)(XnU + lds_off((s0 >> 6) * 64 + lane, (s0 & 63) * 2)) = pk.v;
    }
    __syncthreads();

    // step2 (swapped): C[k][d]; write AX1[d][k] via b64
#pragma unroll
    for (int mi_d = 0; mi_d < 2; ++mi_d) {
        bf16x8 adjf[7];
#pragma unroll
        for (int ks = 0; ks < 7; ++ks) adjf[ks] = u8x8_to_bf16(adjr[mi_d][ks]);
#pragma unroll
        for (int kt = 0; kt < 4; ++kt) {
            f32x4 a2 = fz;
#pragma unroll
            for (int ks = 0; ks < 7; ++ks) {
                bf16x8 af = *(const bf16x8*)(XnU + lds_off(
                    (ks >> 1) * 64 + kt * 16 + frow, ((ks & 1) * 32 + fq * 8) * 2));
                a2 = __builtin_amdgcn_mfma_f32_16x16x32_bf16(af, adjf[ks], a2, 0, 0, 0);
            }
            *(unsigned long long*)(AXU + lds_off(
                wave * 32 + mi_d * 16 + frow, kt * 32 + fq * 8)) = pack4bf(a2);
        }
    }
    __syncthreads();

    // step3: D[f][d] = W1t (x) AX1
    f32x4 acc3[2][16];
#pragma unroll
    for (int i = 0; i < 2; ++i)
#pragma unroll
        for (int j = 0; j < 16; ++j) acc3[i][j] = fz;
#pragma unroll
    for (int ks = 0; ks < 2; ++ks)
#pragma unroll
        for (int ni = 0; ni < 16; ++ni) {
            bf16x8 bfr = *(const bf16x8*)(AXU + lds_off(
                ni * 16 + frow, ks * 64 + fq * 16));
            acc3[0][ni] = __builtin_amdgcn_mfma_f32_16x16x32_bf16(w1f[0][ks], bfr, acc3[0][ni], 0, 0, 0);
            acc3[1][ni] = __builtin_amdgcn_mfma_f32_16x16x32_bf16(w1f[1][ks], bfr, acc3[1][ni], 0, 0, 0);
        }

    // epilogue: X1nT[p][f][d] = relu(acc*nrm_d + b1[f]) * nrm_d  (d<224)
    float nrd[16];
#pragma unroll
    for (int ni = 0; ni < 16; ++ni) {
        int d = ni * 16 + frow;
        nrd[ni] = (d < 200) ? nrm[p * 200 + d] : 0.f;
    }
#pragma unroll
    for (int mi = 0; mi < 2; ++mi)
#pragma unroll
        for (int j = 0; j < 4; ++j) {
            int f = wave * 32 + mi * 16 + r4 + j;
            float bv = b1[f];
#pragma unroll
            for (int ni = 0; ni < 16; ++ni) {
                int d = ni * 16 + frow;
                if (d < 224) {
                    float v = fmaxf(acc3[mi][ni][j] * nrd[ni] + bv, 0.f) * nrd[ni];
                    X1nT[((size_t)p * 256 + f) * 224 + d] = f2bf(v);
                }
            }
        }
}

// --------- fused GCN layer 2 + GAT poi2img (one block per parcel) ----------
// acc5 = f32 PN rows (never written to HBM). Epilogue: el = PN.wu (+er),
// leaky, block softmax, q[h] = sum alpha.PN, pool = mean PN.
__global__ __launch_bounds__(512, 2) void gcnBG_k(
    const unsigned char* __restrict__ Adj, const unsigned short* __restrict__ X1nT,
    const unsigned short* __restrict__ W2t, const float* __restrict__ nrm,
    const float* __restrict__ b2, const float* __restrict__ er,
    const float* __restrict__ wu, float* __restrict__ qout,
    float* __restrict__ pool, unsigned short* __restrict__ poolb)
{
    __shared__ unsigned char BbU[16384];           // X1nT chunk / esh (epi)
    __shared__ unsigned char AXbU[32768];          // AX2 chunk / qsh (epi)
    __shared__ unsigned char W2bU[16384];          // W2 chunk (w2off)
    __shared__ float wush[768];
    __shared__ float mz[8];

    const int tid  = threadIdx.x;
    const int p    = blockIdx.x;
    const int lane = tid & 63;
    const int wave = tid >> 6;
    const int frow = lane & 15;
    const int fq   = lane >> 4;
    const int r4   = fq << 2;
    const f32x4 fz = {0.f, 0.f, 0.f, 0.f};

    // Adj rows (2/lane) pre-converted to bf16 (B-operand frags)
    bf16x8 adjb[2][7];
#pragma unroll
    for (int mi = 0; mi < 2; ++mi) {
        const unsigned char* ar = Adj + ((size_t)p << 16)
            + (size_t)(wave * 32 + mi * 16 + frow) * 256 + fq * 8;
#pragma unroll
        for (int ks = 0; ks < 7; ++ks)
            adjb[mi][ks] = u8x8_to_bf16(*(const uint2*)(ar + ks * 32));
    }

    for (int i = tid; i < 768; i += 512) wush[i] = wu[i];

    f32x4 acc5[2][16];
#pragma unroll
    for (int i = 0; i < 2; ++i)
#pragma unroll
        for (int j = 0; j < 16; ++j) acc5[i][j] = fz;

    // staging address helpers
    auto bbDst = [&](int idx) {                    // idx < 896
        int fl = idx / 28, soct = idx - fl * 28;
        int s0 = soct * 8;
        return lds_off((s0 >> 6) * 32 + fl, (s0 & 63) * 2);
    };
    auto bbSrc = [&](int c, int idx) {
        int fl = idx / 28, soct = idx - fl * 28;
        return (const uint4*)(X1nT + ((size_t)p * 256 + c * 32 + fl) * 224 + soct * 8);
    };

    // prologue: stage chunk 0 (Bb + W2b)
    {
        *(uint4*)(BbU + bbDst(tid)) = *bbSrc(0, tid);
        if (tid < 384) *(uint4*)(BbU + bbDst(tid + 512)) = *bbSrc(0, tid + 512);
#pragma unroll
        for (int i = 0; i < 2; ++i) {
            int idx = tid + i * 512;
            int r = idx >> 2, oct = idx & 3;
            *(uint4*)(W2bU + w2off(r, oct * 16)) =
                *(const uint4*)(W2t + (size_t)r * 256 + oct * 8);
        }
    }
    __syncthreads();

    for (int c = 0; c < 8; ++c) {
        // issue next-chunk Bb loads (hide under step4)
        uint4 stb0, stb1;
        if (c < 7) {
            stb0 = *bbSrc(c + 1, tid);
            if (tid < 384) stb1 = *bbSrc(c + 1, tid + 512);
        }
        // step4 (swapped): C[f][d] per (mi_d, mi_f)
        f32x4 acc4[2][2];
#pragma unroll
        for (int i = 0; i < 2; ++i)
#pragma unroll
            for (int j = 0; j < 2; ++j) acc4[i][j] = fz;
#pragma unroll
        for (int ks = 0; ks < 7; ++ks) {
#pragma unroll
            for (int mi_f = 0; mi_f < 2; ++mi_f) {
                bf16x8 af = *(const bf16x8*)(BbU + lds_off(
                    (ks >> 1) * 32 + mi_f * 16 + frow, ((ks & 1) * 32 + fq * 8) * 2));
                acc4[0][mi_f] = __builtin_amdgcn_mfma_f32_16x16x32_bf16(af, adjb[0][ks], acc4[0][mi_f], 0, 0, 0);
                acc4[1][mi_f] = __builtin_amdgcn_mfma_f32_16x16x32_bf16(af, adjb[1][ks], acc4[1][mi_f], 0, 0, 0);
            }
        }
        __syncthreads();
        // AXb writes (b64, conflict-free) + Bb restage
#pragma unroll
        for (int mi_d = 0; mi_d < 2; ++mi_d)
#pragma unroll
            for (int mi_f = 0; mi_f < 2; ++mi_f)
                *(unsigned long long*)(AXbU + lds_off(
                    wave * 32 + mi_d * 16 + frow, mi_f * 32 + fq * 8))
                    = pack4bf(acc4[mi_d][mi_f]);
        if (c < 7) {
            *(uint4*)(BbU + bbDst(tid)) = stb0;
            if (tid < 384) *(uint4*)(BbU + bbDst(tid + 512)) = stb1;
        }
        __syncthreads();
        // issue next-chunk W2b loads (hide under step5)
        uint4 stw[2];
        if (c < 7) {
#pragma unroll
            for (int i = 0; i < 2; ++i) {
                int idx = tid + i * 512;
                int r = idx >> 2, oct = idx & 3;
                stw[i] = *(const uint4*)(W2t + (size_t)r * 256 + (c + 1) * 32 + oct * 8);
            }
        }
        // step5: acc5 += AX2chunk (x) W2chunk (K=32)
        bf16x8 a5[2];
        a5[0] = *(const bf16x8*)(AXbU + lds_off(wave * 32 + frow, fq * 16));
        a5[1] = *(const bf16x8*)(AXbU + lds_off(wave * 32 + 16 + frow, fq * 16));
#pragma unroll
        for (int ni = 0; ni < 16; ++ni) {
            bf16x8 bfr = *(const bf16x8*)(W2bU + w2off(ni * 16 + frow, fq * 16));
            acc5[0][ni] = __builtin_amdgcn_mfma_f32_16x16x32_bf16(a5[0], bfr, acc5[0][ni], 0, 0, 0);
            acc5[1][ni] = __builtin_amdgcn_mfma_f32_16x16x32_bf16(a5[1], bfr, acc5[1][ni], 0, 0, 0);
        }
        __syncthreads();
        if (c < 7) {
#pragma unroll
            for (int i = 0; i < 2; ++i) {
                int idx = tid + i * 512;
                int r = idx >> 2, oct = idx & 3;
                *(uint4*)(W2bU + w2off(r, oct * 16)) = stw[i];
            }
        }
    }

    // ---------------- fused GAT epilogue (PN stays in registers) -----------
    float* esh = (float*)BbU;                      // [200*3] aliases Bb
    float* qsh = (float*)AXbU;                     // [8][4][256] aliases AXb

    float b2v[16], nrv[2][4];
#pragma unroll
    for (int ni = 0; ni < 16; ++ni) b2v[ni] = b2[ni * 16 + frow];
#pragma unroll
    for (int mi = 0; mi < 2; ++mi)
#pragma unroll
        for (int j = 0; j < 4; ++j) {
            int d = wave * 32 + mi * 16 + r4 + j;
            nrv[mi][j] = (d < 200) ? nrm[p * 200 + d] : 0.f;
        }
    float er3[3];
#pragma unroll
    for (int h = 0; h < 3; ++h) er3[h] = er[p * 3 + h];

    // el pass: e[d][h] = leaky(sum_f v[d][f]*wu[f][h] + er[h])
#pragma unroll
    for (int mi = 0; mi < 2; ++mi)
#pragma unroll
        for (int j = 0; j < 4; ++j) {
            float e0 = 0.f, e1 = 0.f, e2 = 0.f;
            float nr = nrv[mi][j];
#pragma unroll
            for (int ni = 0; ni < 16; ++ni) {
                float vv = acc5[mi][ni][j] * nr + b2v[ni];
                int wb = (ni * 16 + frow) * 3;
                e0 += vv * wush[wb];
                e1 += vv * wush[wb + 1];
                e2 += vv * wush[wb + 2];
            }
#pragma unroll
            for (int o = 1; o < 16; o <<= 1) {
                e0 += __shfl_xor(e0, o);
                e1 += __shfl_xor(e1, o);
                e2 += __shfl_xor(e2, o);
            }
            int d = wave * 32 + mi * 16 + r4 + j;
            if (frow == 0 && d < 200) {
                float t0 = e0 + er3[0]; t0 = t0 > 0.f ? t0 : 0.2f * t0;
                float t1 = e1 + er3[1]; t1 = t1 > 0.f ? t1 : 0.2f * t1;
                float t2 = e2 + er3[2]; t2 = t2 > 0.f ? t2 : 0.2f * t2;
                esh[d * 3 + 0] = t0;
                esh[d * 3 + 1] = t1;
                esh[d * 3 + 2] = t2;
            }
        }
    __syncthreads();

    // block softmax stats (3 waves, one head each)
    if (wave < 3) {
        float mx = -1e30f;
        for (int n = lane; n < 200; n += 64) mx = fmaxf(mx, esh[n * 3 + wave]);
#pragma unroll
        for (int o = 32; o > 0; o >>= 1) mx = fmaxf(mx, __shfl_xor(mx, o));
        float sm = 0.f;
        for (int n = lane; n < 200; n += 64) sm += expf(esh[n * 3 + wave] - mx);
#pragma unroll
        for (int o = 32; o > 0; o >>= 1) sm += __shfl_xor(sm, o);
        if (lane == 0) { mz[wave] = mx; mz[4 + wave] = sm; }
    }
    __syncthreads();

    // alpha per owned d
    float alph[2][4][3];
#pragma unroll
    for (int mi = 0; mi < 2; ++mi)
#pragma unroll
        for (int j = 0; j < 4; ++j) {
            int d = wave * 32 + mi * 16 + r4 + j;
#pragma unroll
            for (int h = 0; h < 3; ++h)
                alph[mi][j][h] = (d < 200)
                    ? expf(esh[d * 3 + h] - mz[h]) / (mz[4 + h] + 1e-9f) : 0.f;
        }

    // q/pool pass: coef c in {h0,h1,h2,pool(1/200)}
#pragma unroll
    for (int cfn = 0; cfn < 4; ++cfn) {
        float qacc[16];
#pragma unroll
        for (int ni = 0; ni < 16; ++ni) qacc[ni] = 0.f;
        float csum = 0.f;
#pragma unroll
        for (int mi = 0; mi < 2; ++mi)
#pragma unroll
            for (int j = 0; j < 4; ++j) {
                int d = wave * 32 + mi * 16 + r4 + j;
                float coef = 0.f;
                if (d < 200) coef = (cfn < 3) ? alph[mi][j][cfn] : 0.005f;
                float cn = coef * nrv[mi][j];
                csum += coef;
#pragma unroll
                for (int ni = 0; ni < 16; ++ni)
                    qacc[ni] += cn * acc5[mi][ni][j];
            }
#pragma unroll
        for (int ni = 0; ni < 16; ++ni) {
            float v = qacc[ni] + csum * b2v[ni];
            v += __shfl_xor(v, 16);
            v += __shfl_xor(v, 32);
            if (fq == 0) qsh[wave * 1024 + cfn * 256 + ni * 16 + frow] = v;
        }
    }
    __syncthreads();

    // final reduce across waves; write q + pool
    for (int i = tid; i < 1024; i += 512) {
        int cfn = i >> 8, f = i & 255;
        float s = 0.f;
#pragma unroll
        for (int w = 0; w < 8; ++w) s += qsh[w * 1024 + cfn * 256 + f];
        if (cfn < 3) {
            qout[(size_t)p * 768 + cfn * 256 + f] = s;
        } else {
            pool[(size_t)p * 256 + f] = s;
            poolb[(size_t)p * 256 + f] = f2bf(s);
        }
    }
}

// ----------------------- 64x64 MFMA GEMM (small shapes) ---------------------
template<bool ABF16, bool BBF16, int OMODE, bool BIASF, bool RELUF,
         bool MEDOUT, int KCHUNK>
__global__ __launch_bounds__(256) void mm64_k(
    const void* __restrict__ Ain, const void* __restrict__ Bin,
    void* __restrict__ Cout, int M, int Nc, int K,
    const float* __restrict__ bias, float alpha)
{
    __shared__ bf16x8 smem_v[1024];                 // 16 KiB
    unsigned char* Asm = (unsigned char*)smem_v;
    unsigned char* Bsm = Asm + 8192;

    const int tid  = threadIdx.x;
    const int m0   = blockIdx.y * 64;
    const int n0   = blockIdx.x * 64;
    const int sr   = tid >> 3, sc = tid & 7;
    const int lane = tid & 63;
    const int wm   = (tid >> 7) & 1, wn = (tid >> 6) & 1;
    const int frow = lane & 15;
    const int fko  = (lane >> 4) << 4;

    int kbeg = 0, kend = K;
    float* Cf = (float*)Cout;
    if (KCHUNK > 0) {
        kbeg = blockIdx.z * KCHUNK; kend = kbeg + KCHUNK;
        Cf += (size_t)blockIdx.z * M * Nc;
    }

    f32x4 acc[2][2];
    const f32x4 fz = {0.f, 0.f, 0.f, 0.f};
#pragma unroll
    for (int i = 0; i < 2; ++i)
#pragma unroll
        for (int j = 0; j < 2; ++j) acc[i][j] = fz;

    bf16x8 areg[2], breg[2];
    auto load_tiles = [&](int k0) {
#pragma unroll
        for (int i = 0; i < 2; ++i) {
            int row = sr + 32 * i;
            areg[i] = load_row8<ABF16>(Ain, (size_t)(m0 + row) * K + k0 + sc * 8);
            breg[i] = load_row8<BBF16>(Bin, (size_t)(n0 + row) * K + k0 + sc * 8);
        }
    };

    load_tiles(kbeg);
    for (int k0 = kbeg; k0 < kend; k0 += 64) {
        __syncthreads();
#pragma unroll
        for (int i = 0; i < 2; ++i) {
            *(bf16x8*)(Asm + lds_off(sr + 32 * i, sc * 16)) = areg[i];
            *(bf16x8*)(Bsm + lds_off(sr + 32 * i, sc * 16)) = breg[i];
        }
        __syncthreads();
        if (k0 + 64 < kend) load_tiles(k0 + 64);
#pragma unroll
        for (int ks = 0; ks < 2; ++ks) {
            const int kb = ks * 64 + fko;
            bf16x8 af[2], bfr[2];
#pragma unroll
            for (int t = 0; t < 2; ++t)
                af[t] = *(const bf16x8*)(Asm + lds_off(wm * 32 + t * 16 + frow, kb));
#pragma unroll
            for (int t = 0; t < 2; ++t)
                bfr[t] = *(const bf16x8*)(Bsm + lds_off(wn * 32 + t * 16 + frow, kb));
#pragma unroll
            for (int mi = 0; mi < 2; ++mi)
#pragma unroll
                for (int ni = 0; ni < 2; ++ni)
                    acc[mi][ni] = __builtin_amdgcn_mfma_f32_16x16x32_bf16(
                        af[mi], bfr[ni], acc[mi][ni], 0, 0, 0);
        }
    }

    const int r4 = (lane >> 4) << 2;
#pragma unroll
    for (int mi = 0; mi < 2; ++mi) {
#pragma unroll
        for (int ni = 0; ni < 2; ++ni) {
            int col = n0 + wn * 32 + ni * 16 + frow;
#pragma unroll
            for (int j = 0; j < 4; ++j) {
                int row = m0 + wm * 32 + mi * 16 + r4 + j;
                float v = acc[mi][ni][j] * alpha;
                if (BIASF)  v += bias[col];
                if (RELUF)  v = fmaxf(v, 0.f);
                if (MEDOUT) v += 0.5f;
                if (OMODE == 0) {
                    Cf[(size_t)row * Nc + col] = v;
                } else {
                    ((unsigned short*)Cout)[(size_t)row * Nc + col] = f2bf(v);
                }
            }
        }
    }
}

// ------------------------- graph preprocessing -----------------------------
__global__ __launch_bounds__(256) void edge_diag_k(
    const int* __restrict__ esrc, const int* __restrict__ edst,
    unsigned char* __restrict__ A)
{
    int id = blockIdx.x * 256 + threadIdx.x;        // E + N = 1740800
    size_t bo;
    if (id < E_EDGES) {
        int s = esrc[id], d = edst[id];
        int p = d / 200;
        int dl = d - p * 200, sl = s - p * 200;
        bo = (((size_t)(p * 256 + dl)) << 8) + (unsigned)sl;
    } else {
        int i2 = id - E_EDGES;                      // < N
        int p = i2 / 200, d = i2 - p * 200;
        bo = (((size_t)(p * 256 + d)) << 8) + (unsigned)d;
    }
    atomicAdd((unsigned int*)(A + (bo & ~(size_t)3)), 1u << ((bo & 3) * 8));
}

__global__ __launch_bounds__(256) void norm2_k(const unsigned char* __restrict__ A,
                                               float* __restrict__ nrm)
{
    int g = blockIdx.x * 256 + threadIdx.x;
    int p = g / 200, d = g - p * 200;
    const uint4* row = (const uint4*)(A + (((size_t)(p * 256 + d)) << 8));
    unsigned s = 0;
#pragma unroll
    for (int i = 0; i < 16; ++i) {
        uint4 w = row[i];
        unsigned a = w.x, b = w.y, c = w.z, e = w.w;
        s += (a & 255) + ((a >> 8) & 255) + ((a >> 16) & 255) + (a >> 24);
        s += (b & 255) + ((b >> 8) & 255) + ((b >> 16) & 255) + (b >> 24);
        s += (c & 255) + ((c >> 8) & 255) + ((c >> 16) & 255) + (c >> 24);
        s += (e & 255) + ((e >> 8) & 255) + ((e >> 16) & 255) + (e >> 24);
    }
    nrm[g] = rsqrtf((float)s);                      // row-sum = in-deg + self
}

// ------------- all weight transposes/casts + img cast -----------------------
__global__ __launch_bounds__(256) void prep_k(
    const float* __restrict__ W1, const float* __restrict__ W2,
    const float* __restrict__ Whg,
    const float* __restrict__ Wpg, const float* __restrict__ Whrs,
    const float* __restrict__ Wgin, const float* __restrict__ Wgw,
    const float* __restrict__ Wph, const float* __restrict__ img,
    unsigned short* __restrict__ W1t, unsigned short* __restrict__ W2t,
    unsigned short* __restrict__ Whgt,
    unsigned short* __restrict__ Wpgt, unsigned short* __restrict__ Whrst,
    unsigned short* __restrict__ Wgint, unsigned short* __restrict__ Wmt,
    unsigned short* __restrict__ Wphb, unsigned short* __restrict__ imgb)
{
    int b = blockIdx.x, tid = threadIdx.x;
    if (b < 64) {                 // W1t [256][64]
        int id = b * 256 + tid; int n = id >> 6, k = id & 63;
        W1t[id] = f2bf(W1[(size_t)k * 256 + n]);
    } else if (b < 320) {         // W2t [256][256]
        int id = (b - 64) * 256 + tid; int n = id >> 8, k = id & 255;
        W2t[id] = f2bf(W2[(size_t)k * 256 + n]);
    } else if (b < 576) {         // Whgt
        int id = (b - 320) * 256 + tid; int n = id >> 8, k = id & 255;
        Whgt[id] = f2bf(Whg[(size_t)k * 256 + n]);
    } else if (b < 832) {         // Wpgt
        int id = (b - 576) * 256 + tid; int n = id >> 8, k = id & 255;
        Wpgt[id] = f2bf(Wpg[(size_t)k * 256 + n]);
    } else if (b < 2880) {        // Whrst [256][2048]
        int id = (b - 832) * 256 + tid; int n = id >> 11, k = id & 2047;
        Whrst[id] = f2bf(Whrs[(size_t)k * 256 + n]);
    } else if (b < 3648) {        // Wgint [256][768], k-order = h*256+t
        int id = (b - 2880) * 256 + tid; int j = id / 768, k2 = id - j * 768;
        int t = k2 & 255, h = k2 >> 8;
        Wgint[id] = f2bf(Wgin[(size_t)t * 768 + h * 256 + j]);
    } else if (b < 3904) {        // Wmt [256 j][256 t] = mean_h Wgw / (1+1e-9)
        int id = (b - 3648) * 256 + tid; int j = id >> 8, t = id & 255;
        const float c3 = (1.f / 3.f) * (1.f / (1.f + 1e-9f));
        float s = Wgw[(size_t)t * 768 + j] + Wgw[(size_t)t * 768 + 256 + j] +
                  Wgw[(size_t)t * 768 + 512 + j];
        Wmt[id] = f2bf(s * c3);
    } else if (b < 4160) {        // Wphb cast
        int id = (b - 3904) * 256 + tid;
        Wphb[id] = f2bf(Wph[id]);
    } else {                      // imgb cast [512][2048]
        int id = (b - 4160) * 256 + tid;
        imgb[id] = f2bf(img[id]);
    }
}

// --- WpG[j][(h,c)] = sum_t Wpp[c][t]*Wgin[t][h*256+j]; bgg[j] (bias fold) ----
__global__ __launch_bounds__(256) void wpg_k(
    const float* __restrict__ Wpp, const float* __restrict__ Wgin,
    const float* __restrict__ bpp,
    unsigned short* __restrict__ WpG, float* __restrict__ bgg)
{
    __shared__ float wsh[256];
    const int b = blockIdx.x, j = threadIdx.x;
    if (b < 768) {
        int h = b >> 8, c = b & 255;
        wsh[j] = Wpp[(size_t)c * 256 + j];
        __syncthreads();
        float acc = 0.f;
        for (int t = 0; t < 256; ++t)
            acc += wsh[t] * Wgin[(size_t)t * 768 + h * 256 + j];
        WpG[(size_t)j * 768 + h * 256 + c] = f2bf(acc);
    } else {
        float s = 0.f;
        for (int h = 0; h < 3; ++h)
            for (int t = 0; t < 256; ++t)
                s += bpp[t] * Wgin[(size_t)t * 768 + h * 256 + j];
        bgg[j] = s * (1.f / 3.f);
    }
}

// --------------------------- hrs split-K reduce -----------------------------
__global__ __launch_bounds__(256) void hrs_reduce_k(
    const float* __restrict__ part, const float* __restrict__ bhrs,
    float* __restrict__ hrs, unsigned short* __restrict__ hrsb)
{
    int id = blockIdx.x * 256 + threadIdx.x;        // 131072
    float s = bhrs[id & 255];
#pragma unroll
    for (int z = 0; z < 8; ++z) s += part[(size_t)z * 131072 + id];
    hrs[id] = s;
    hrsb[id] = f2bf(s);
}

// ------------------- med = rownorm(concat(hrs, pool)) -----------------------
__global__ __launch_bounds__(256) void med_build_k(
    const float* __restrict__ hrs, const float* __restrict__ pool,
    unsigned short* __restrict__ medb)
{
    __shared__ float red[256];
    int b = blockIdx.x, f = threadIdx.x;
    float v0 = hrs[(size_t)b * 256 + f];
    float v1 = pool[(size_t)b * 256 + f];
    red[f] = v0 * v0 + v1 * v1;
    __syncthreads();
    for (int s = 128; s > 0; s >>= 1) {
        if (f < s) red[f] += red[f + s];
        __syncthreads();
    }
    float inv = rsqrtf(red[0]);
    medb[(size_t)b * 512 + f]       = f2bf(v0 * inv);
    medb[(size_t)b * 512 + 256 + f] = f2bf(v1 * inv);
}

// ---------------------- thresholded-similarity GCN --------------------------
__global__ __launch_bounds__(256) void dinv_k(const float* __restrict__ mo,
                                              float* __restrict__ dinv)
{
    __shared__ int red[256];
    int i = blockIdx.x, t = threadIdx.x;
    int c = 0;
    for (int j = t; j < 512; j += 256) c += (mo[(size_t)i * 512 + j] >= 0.9f) ? 1 : 0;
    red[t] = c; __syncthreads();
    for (int s = 128; s > 0; s >>= 1) {
        if (t < s) red[t] += red[t + s];
        __syncthreads();
    }
    if (t == 0) dinv[i] = rsqrtf((float)red[0]);
}

__global__ __launch_bounds__(256) void nadj_k(const float* __restrict__ mo,
                                              const float* __restrict__ dinv,
                                              unsigned short* __restrict__ nadjb)
{
    int i = blockIdx.x, t = threadIdx.x;
    float di = dinv[i];
    for (int j = t; j < 512; j += 256) {
        float a = (mo[(size_t)i * 512 + j] >= 0.9f || j == i) ? 1.f : 0.f;
        nadjb[(size_t)i * 512 + j] = f2bf(a * di * dinv[j]);
    }
}

// ---------------- GAT precomputes: wave-parallel dot products ---------------
__global__ __launch_bounds__(256) void uv1_k(
    const float* __restrict__ Wgin, const float* __restrict__ al,
    const float* __restrict__ ar,
    float* __restrict__ u2, float* __restrict__ v2)
{
    const int wave = threadIdx.x >> 6, lane = threadIdx.x & 63;
    const int task = blockIdx.x * 4 + wave;         // < 768
    const int k = task / 3, h = task - k * 3;
    float4 w = *(const float4*)(Wgin + (size_t)k * 768 + h * 256 + lane * 4);
    float4 a = *(const float4*)(al + h * 256 + lane * 4);
    float4 r = *(const float4*)(ar + h * 256 + lane * 4);
    float su = w.x * a.x + w.y * a.y + w.z * a.z + w.w * a.w;
    float sv = w.x * r.x + w.y * r.y + w.z * r.z + w.w * r.w;
#pragma unroll
    for (int o = 32; o > 0; o >>= 1) {
        su += __shfl_xor(su, o);
        sv += __shfl_xor(sv, o);
    }
    if (lane == 0) { u2[task] = su; v2[task] = sv; }
}

__global__ __launch_bounds__(256) void uv2_k(
    const float* __restrict__ Wph, const float* __restrict__ Wpp,
    const float* __restrict__ bph, const float* __restrict__ bpp,
    const unsigned short* __restrict__ Wmt,
    const float* __restrict__ u2, const float* __restrict__ v2,
    float* __restrict__ vv2, float* __restrict__ wu,
    float* __restrict__ bc, float* __restrict__ erb, float* __restrict__ eb0)
{
    __shared__ float ush[768], vsh[768];
    const int tid = threadIdx.x;
    for (int i = tid; i < 768; i += 256) { ush[i] = u2[i]; vsh[i] = v2[i]; }
    __syncthreads();
    const int wave = tid >> 6, lane = tid & 63;
    const int task = blockIdx.x * 4 + wave;
    float s = 0.f;
    if (task < 1536) {
        int t2 = task < 768 ? task : task - 768;
        int k = t2 / 3, h = t2 - k * 3;
        const float* W = task < 768 ? Wph : Wpp;
        const float* vec = task < 768 ? vsh : ush;
        float4 w = *(const float4*)(W + (size_t)k * 256 + lane * 4);
        s = w.x * vec[(lane * 4 + 0) * 3 + h] + w.y * vec[(lane * 4 + 1) * 3 + h]
          + w.z * vec[(lane * 4 + 2) * 3 + h] + w.w * vec[(lane * 4 + 3) * 3 + h];
#pragma unroll
        for (int o = 32; o > 0; o >>= 1) s += __shfl_xor(s, o);
        if (lane == 0) { if (task < 768) vv2[t2] = s; else wu[t2] = s; }
    } else if (task < 1792) {
        int k = task - 1536;
        float4 b4 = *(const float4*)(bph + lane * 4);
        const unsigned short* wm = Wmt + (size_t)k * 256 + lane * 4;
        s = b4.x * bf2f(wm[0]) + b4.y * bf2f(wm[1])
          + b4.z * bf2f(wm[2]) + b4.w * bf2f(wm[3]);
#pragma unroll
        for (int o = 32; o > 0; o >>= 1) s += __shfl_xor(s, o);
        if (lane == 0) bc[k] = s;
    } else if (task < 1798) {
        int t2 = task - 1792;
        int h = t2 % 3;
        bool second = t2 >= 3;
        const float* bias = second ? bpp : bph;
        const float* vec  = second ? ush : vsh;
        float4 b4 = *(const float4*)(bias + lane * 4);
        s = b4.x * vec[(lane * 4 + 0) * 3 + h] + b4.y * vec[(lane * 4 + 1) * 3 + h]
          + b4.z * vec[(lane * 4 + 2) * 3 + h] + b4.w * vec[(lane * 4 + 3) * 3 + h];
#pragma unroll
        for (int o = 32; o > 0; o >>= 1) s += __shfl_xor(s, o);
        if (lane == 0) { if (second) eb0[h] = s; else erb[h] = s; }
    }
}

__global__ __launch_bounds__(256) void er2_k(
    const float* __restrict__ hrs, const float* __restrict__ vv2,
    const float* __restrict__ erb, const float* __restrict__ eb0,
    float* __restrict__ er)
{
    __shared__ float vsh[768];
    const int tid = threadIdx.x;
    for (int i = tid; i < 768; i += 256) vsh[i] = vv2[i];
    __syncthreads();
    const int wave = tid >> 6, lane = tid & 63;
    const int task = blockIdx.x * 4 + wave;         // < 1536
    const int b = task / 3, h = task - b * 3;
    float4 hv = *(const float4*)(hrs + (size_t)b * 256 + lane * 4);
    float s = hv.x * vsh[(lane * 4 + 0) * 3 + h] + hv.y * vsh[(lane * 4 + 1) * 3 + h]
            + hv.z * vsh[(lane * 4 + 2) * 3 + h] + hv.w * vsh[(lane * 4 + 3) * 3 + h];
#pragma unroll
    for (int o = 32; o > 0; o >>= 1) s += __shfl_xor(s, o);
    if (lane == 0) er[task] = erb[h] + eb0[h] + s;
}

// --------------------------- final projection -------------------------------
__global__ __launch_bounds__(256) void final_k(
    const float* __restrict__ i2p, const float* __restrict__ hpagg,
    const float* __restrict__ p2i,
    const float* __restrict__ Wfc, const float* __restrict__ bfc,
    float* __restrict__ out)
{
    int id = blockIdx.x * 256 + threadIdx.x;
    if (id >= B_PAR * 12) return;
    int b = id / 12, o = id % 12;
    float acc = bfc[o];
    const float* s0 = i2p + (size_t)b * 256;          // img2poi_pooled
    const float* s1 = hpagg + (size_t)b * 512 + 256;  // poi_agg
    const float* s2 = p2i + (size_t)b * 256;          // poi2img
    const float* s3 = hpagg + (size_t)b * 512;        // hrs_agg
    for (int k = 0; k < 256; ++k) {
        acc += s0[k] * Wfc[(size_t)(0 * 256 + k) * 12 + o];
        acc += s1[k] * Wfc[(size_t)(1 * 256 + k) * 12 + o];
        acc += s2[k] * Wfc[(size_t)(2 * 256 + k) * 12 + o];
        acc += s3[k] * Wfc[(size_t)(3 * 256 + k) * 12 + o];
    }
    out[id] = acc;
}

// ---------------------------------------------------------------------------
extern "C" void kernel_launch(void* const* d_in, const int* in_sizes, int n_in,
                              void* d_out, int out_size, void* d_ws, size_t ws_size,
                              hipStream_t stream)
{
    const float* g_poi = (const float*)d_in[0];
    const float* img   = (const float*)d_in[1];
    const int*   esrc  = (const int*)d_in[2];
    const int*   edst  = (const int*)d_in[3];
    const float* W1    = (const float*)d_in[4];
    const float* b1    = (const float*)d_in[5];
    const float* W2    = (const float*)d_in[6];
    const float* b2    = (const float*)d_in[7];
    const float* Whrs  = (const float*)d_in[8];
    const float* bhrs  = (const float*)d_in[9];
    const float* Wph   = (const float*)d_in[10];
    const float* bph   = (const float*)d_in[11];
    const float* Wpp   = (const float*)d_in[12];
    const float* bpp   = (const float*)d_in[13];
    const float* Wgin  = (const float*)d_in[14];
    const float* alin  = (const float*)d_in[15];
    const float* arin  = (const float*)d_in[16];
    const float* Wgw   = (const float*)d_in[17];
    // d_in[18]/d_in[19] (al_with/ar_with) numerically dead: each poi node has
    // exactly one incoming parcel edge -> edge-softmax weight = 1/(1+1e-9).
    const float* Whg   = (const float*)d_in[20];
    const float* Wpg   = (const float*)d_in[21];
    const float* Wfc   = (const float*)d_in[22];
    const float* bfc   = (const float*)d_in[23];

    float* out     = (float*)d_out;
    float* med_out = out + B_PAR * 12;

    char* ws = (char*)d_ws;
    size_t off = 0;
    auto take = [&](size_t bytes) { void* pv = ws + off; off += (bytes + 255) & ~(size_t)255; return pv; };

    unsigned char*  adj8 = (unsigned char*)take((size_t)B_PAR * 256 * 256);     // 33.6MB
    unsigned short* X1nT = (unsigned short*)take((size_t)B_PAR * 256 * 224 * 2);// 58.7MB
    float*          part = (float*)take((size_t)8 * 512 * 256 * 4);             // 4.2MB

    unsigned short* W1t   = (unsigned short*)take(256 * 64 * 2);
    unsigned short* W2t   = (unsigned short*)take(256 * 256 * 2);
    unsigned short* Whgt  = (unsigned short*)take(256 * 256 * 2);
    unsigned short* Wpgt  = (unsigned short*)take(256 * 256 * 2);
    unsigned short* Whrst = (unsigned short*)take((size_t)256 * 2048 * 2);
    unsigned short* Wgint = (unsigned short*)take((size_t)256 * 768 * 2);
    unsigned short* Wmt   = (unsigned short*)take(256 * 256 * 2);
    unsigned short* Wphb  = (unsigned short*)take(256 * 256 * 2);
    unsigned short* WcT   = (unsigned short*)take(256 * 256 * 2);
    unsigned short* WpG   = (unsigned short*)take((size_t)256 * 768 * 2);
    unsigned short* imgb  = (unsigned short*)take((size_t)512 * 2048 * 2);
    unsigned short* hrsb  = (unsigned short*)take((size_t)B_PAR * 256 * 2);
    unsigned short* poolb = (unsigned short*)take((size_t)B_PAR * 256 * 2);
    unsigned short* medb  = (unsigned short*)take((size_t)B_PAR * 512 * 2);
    unsigned short* nadjb = (unsigned short*)take((size_t)B_PAR * 512 * 2);
    unsigned short* Tcatt = (unsigned short*)take((size_t)512 * 512 * 2);
    float* nrm   = (float*)take((size_t)N_NODES * 4);
    float* hrs   = (float*)take((size_t)B_PAR * 256 * 4);
    float* pool  = (float*)take((size_t)B_PAR * 256 * 4);
    float* dinv  = (float*)take((size_t)B_PAR * 4);
    float* hpagg = (float*)take((size_t)B_PAR * 512 * 4);
    float* u2    = (float*)take(768 * 4);
    float* v2    = (float*)take(768 * 4);
    float* wu    = (float*)take(768 * 4);
    float* vv2   = (float*)take(768 * 4);
    float* erb   = (float*)take(16);
    float* eb0   = (float*)take(16);
    float* bc    = (float*)take(256 * 4);
    float* bgg   = (float*)take(256 * 4);
    float* er    = (float*)take((size_t)B_PAR * 3 * 4);
    float* q     = (float*)take((size_t)B_PAR * 768 * 4);
    float* p2i   = (float*)take((size_t)B_PAR * 256 * 4);
    float* i2p   = (float*)take((size_t)B_PAR * 256 * 4);
    (void)ws_size; (void)in_sizes; (void)n_in; (void)out_size;

    // ---- preprocessing ----
    hipMemsetAsync(adj8, 0, (size_t)B_PAR * 256 * 256, stream);
    prep_k<<<8256, 256, 0, stream>>>(W1, W2, Whg, Wpg, Whrs, Wgin, Wgw,
        Wph, img, W1t, W2t, Whgt, Wpgt, Whrst, Wgint, Wmt, Wphb, imgb);
    edge_diag_k<<<(E_EDGES + N_NODES) / 256, 256, 0, stream>>>(esrc, edst, adj8);
    norm2_k<<<N_NODES / 256, 256, 0, stream>>>(adj8, nrm);
    wpg_k<<<769, 256, 0, stream>>>(Wpp, Wgin, bpp, WpG, bgg);

    // ---- hrs encoder: split-K (8x256) 64-tile MFMA + reduce ----
    mm64_k<true, true, 0, false, false, false, 256>
        <<<dim3(4, 8, 8), 256, 0, stream>>>(imgb, Whrst, part, 512, 256, 2048,
            nullptr, 1.f);
    hrs_reduce_k<<<512, 256, 0, stream>>>(part, bhrs, hrs, hrsb);

    // ---- GAT precomputes (wave-parallel) ----
    uv1_k<<<192, 256, 0, stream>>>(Wgin, alin, arin, u2, v2);
    uv2_k<<<450, 256, 0, stream>>>(Wph, Wpp, bph, bpp, Wmt, u2, v2,
                                   vv2, wu, bc, erb, eb0);
    er2_k<<<384, 256, 0, stream>>>(hrs, vv2, erb, eb0, er);
    // WcT[j][c] = (Wph @ Wm)[c][j]
    mm64_k<true, true, 1, false, false, false, 0>
        <<<dim3(4, 4), 256, 0, stream>>>(Wmt, Wphb, WcT, 256, 256, 256,
            nullptr, 1.f);

    // ---- fused GCN L1 -> X1nT ; L2 + GAT poi2img + pool (PN never stored) --
    gcnA_k<<<B_PAR, 512, 0, stream>>>(adj8, g_poi, nrm, W1t, b1, X1nT);
    gcnBG_k<<<B_PAR, 512, 0, stream>>>(adj8, X1nT, W2t, nrm, b2, er, wu,
                                       q, pool, poolb);

    // ---- med similarity (output 1) ----
    med_build_k<<<B_PAR, 256, 0, stream>>>(hrs, pool, medb);
    mm64_k<true, true, 0, false, false, true, 0>
        <<<dim3(8, 8), 256, 0, stream>>>(medb, medb, med_out, 512, 512, 512,
            nullptr, 0.5f);

    // ---- UniSimGraph GCN ----
    dinv_k<<<B_PAR, 256, 0, stream>>>(med_out, dinv);
    nadj_k<<<B_PAR, 256, 0, stream>>>(med_out, dinv, nadjb);
    mm64_k<true, true, 1, false, false, false, 0>
        <<<dim3(8, 4), 256, 0, stream>>>(Whgt, hrsb, Tcatt, 256, 512, 256,
            nullptr, 1.f);
    mm64_k<true, true, 1, false, false, false, 0>
        <<<dim3(8, 4), 256, 0, stream>>>(Wpgt, poolb, Tcatt + (size_t)256 * 512,
            256, 512, 256, nullptr, 1.f);
    mm64_k<true, true, 0, false, true, false, 0>
        <<<dim3(8, 8), 256, 0, stream>>>(nadjb, Tcatt, hpagg, 512, 512, 512,
            nullptr, 1.f);

    // ---- p2i = (1/3) q @ WpG + bgg ----
    mm64_k<false, true, 0, true, false, false, 0>
        <<<dim3(4, 8), 256, 0, stream>>>(q, WpG, p2i, 512, 256, 768,
            bgg, 1.f / 3.f);

    // ---- img2poi pooled: i2p = hrs @ Wc + bc ----
    mm64_k<true, true, 0, true, false, false, 0>
        <<<dim3(4, 8), 256, 0, stream>>>(hrsb, WcT, i2p, 512, 256, 256,
            bc, 1.f);

    // ---- final fc ----
    final_k<<<24, 256, 0, stream>>>(i2p, hpagg, p2i, Wfc, bfc, out);
}